// Round 1
// baseline (393.233 us; speedup 1.0000x reference)
//
#include <hip/hip_runtime.h>

#define M_ROWS 32768   // B*S
#define DIN 1024
#define DC 64
#define KC 4096

// ---------------------------------------------------------------------------
// Transpose emb [KC][DC] -> embT [DC][KC] for coalesced staging later.
__global__ __launch_bounds__(256) void k_transpose_emb(const float* __restrict__ emb,
                                                       float* __restrict__ embT) {
    __shared__ float t[64][68];
    int k0 = blockIdx.x * 64;     // 64 blocks, 64 codes each
    int tid = threadIdx.x;
    for (int q = tid; q < 1024; q += 256) {
        int r = q >> 4, c4 = q & 15;
        float4 v = *(const float4*)&emb[(size_t)(k0 + r) * DC + c4 * 4];
        t[r][c4*4+0] = v.x; t[r][c4*4+1] = v.y; t[r][c4*4+2] = v.z; t[r][c4*4+3] = v.w;
    }
    __syncthreads();
    for (int q = tid; q < 1024; q += 256) {
        int c = q >> 4, k4 = q & 15;
        float4 v;
        v.x = t[k4*4+0][c]; v.y = t[k4*4+1][c]; v.z = t[k4*4+2][c]; v.w = t[k4*4+3][c];
        *(float4*)&embT[(size_t)c * KC + k0 + k4*4] = v;
    }
}

// ---------------------------------------------------------------------------
// sqr[k] = sum_c emb[k][c]^2   (reads embT coalesced)
__global__ __launch_bounds__(256) void k_sqr(const float* __restrict__ embT,
                                             float* __restrict__ sqr) {
    int k = blockIdx.x * 256 + threadIdx.x;
    float s = 0.f;
    #pragma unroll 8
    for (int c = 0; c < DC; ++c) {
        float e = embT[(size_t)c * KC + k];
        s += e * e;
    }
    sqr[k] = s;
}

// ---------------------------------------------------------------------------
// z = input @ W_send + b_send   [32768,1024]x[1024,64]
// Tile: BM=64 rows, BN=64 (all), BK=32. 256 threads, each 4x4 micro-tile.
__global__ __launch_bounds__(256) void k_send(const float* __restrict__ in,
                                              const float* __restrict__ Ws,
                                              const float* __restrict__ bs,
                                              float* __restrict__ z) {
    __shared__ float As[32][68];   // [k][row], padded for alignment+banks
    __shared__ float Bs[32][64];   // [k][col]
    int row0 = blockIdx.x * 64;
    int tid = threadIdx.x;
    int tx = tid & 15;    // row group: rows tx*4..+3
    int ty = tid >> 4;    // col group: cols ty*4..+3 (16*4=64)
    float bias[4];
    #pragma unroll
    for (int j = 0; j < 4; ++j) bias[j] = bs[ty*4 + j];

    float acc[4][4] = {};
    for (int k0 = 0; k0 < DIN; k0 += 32) {
        for (int q = tid; q < 512; q += 256) {         // A: 64 rows x 32 k
            int r = q >> 3, c4 = q & 7;
            float4 v = *(const float4*)&in[(size_t)(row0 + r) * DIN + k0 + c4*4];
            As[c4*4+0][r] = v.x; As[c4*4+1][r] = v.y;
            As[c4*4+2][r] = v.z; As[c4*4+3][r] = v.w;
        }
        for (int q = tid; q < 512; q += 256) {         // B: 32 k x 64 cols
            int kr = q >> 4, c4 = q & 15;
            *(float4*)&Bs[kr][c4*4] = *(const float4*)&Ws[(size_t)(k0 + kr) * DC + c4*4];
        }
        __syncthreads();
        #pragma unroll
        for (int k = 0; k < 32; ++k) {
            float4 av = *(const float4*)&As[k][tx*4];
            float4 bv = *(const float4*)&Bs[k][ty*4];
            float a[4] = {av.x, av.y, av.z, av.w};
            float b[4] = {bv.x, bv.y, bv.z, bv.w};
            #pragma unroll
            for (int i = 0; i < 4; ++i)
                #pragma unroll
                for (int j = 0; j < 4; ++j)
                    acc[i][j] += a[i] * b[j];
        }
        __syncthreads();
    }
    #pragma unroll
    for (int i = 0; i < 4; ++i) {
        int r = row0 + tx*4 + i;
        float4 o;
        o.x = acc[i][0] + bias[0];
        o.y = acc[i][1] + bias[1];
        o.z = acc[i][2] + bias[2];
        o.w = acc[i][3] + bias[3];
        *(float4*)&z[(size_t)r * DC + ty*4] = o;
    }
}

// ---------------------------------------------------------------------------
// argmin_k  sqr[k] - 2*<z_row, emb_k>. 64 rows/block, codes chunked by 128.
__global__ __launch_bounds__(256) void k_argmin(const float* __restrict__ z,
                                                const float* __restrict__ embT,
                                                const float* __restrict__ sqr,
                                                int* __restrict__ idx,
                                                float* __restrict__ out_idx,
                                                int* __restrict__ counts) {
    __shared__ float Zs[64][68];    // [dim][row]
    __shared__ float Es[64][132];   // [dim][code]
    __shared__ float Sq[128];
    __shared__ float redv[16][64];
    __shared__ int   redi[16][64];

    int row0 = blockIdx.x * 64;
    int tid = threadIdx.x;
    int tx = tid & 15;    // rows tx*4..+3
    int ty = tid >> 4;    // codes (within chunk) ty*8..+7

    for (int q = tid; q < 1024; q += 256) {   // load z tile transposed
        int r = q >> 4, c4 = q & 15;
        float4 v = *(const float4*)&z[(size_t)(row0 + r) * DC + c4*4];
        Zs[c4*4+0][r] = v.x; Zs[c4*4+1][r] = v.y;
        Zs[c4*4+2][r] = v.z; Zs[c4*4+3][r] = v.w;
    }

    float bestv[4];
    int   besti[4];
    #pragma unroll
    for (int i = 0; i < 4; ++i) { bestv[i] = 3.402823466e38f; besti[i] = 0; }

    for (int ch = 0; ch < KC / 128; ++ch) {
        int code0 = ch * 128;
        for (int q = tid; q < 2048; q += 256) {   // emb chunk, dim-major
            int c = q >> 5, k4 = q & 31;
            *(float4*)&Es[c][k4*4] =
                *(const float4*)&embT[(size_t)c * KC + code0 + k4*4];
        }
        if (tid < 128) Sq[tid] = sqr[code0 + tid];
        __syncthreads();

        float dot[4][8] = {};
        #pragma unroll 8
        for (int c = 0; c < 64; ++c) {
            float4 zv = *(const float4*)&Zs[c][tx*4];
            float4 e0 = *(const float4*)&Es[c][ty*8];
            float4 e1 = *(const float4*)&Es[c][ty*8 + 4];
            float zr[4] = {zv.x, zv.y, zv.z, zv.w};
            float ee[8] = {e0.x, e0.y, e0.z, e0.w, e1.x, e1.y, e1.z, e1.w};
            #pragma unroll
            for (int i = 0; i < 4; ++i)
                #pragma unroll
                for (int j = 0; j < 8; ++j)
                    dot[i][j] += zr[i] * ee[j];
        }

        #pragma unroll
        for (int j = 0; j < 8; ++j) {
            float sq = Sq[ty*8 + j];
            int code = code0 + ty*8 + j;
            #pragma unroll
            for (int i = 0; i < 4; ++i) {
                float s = sq - 2.0f * dot[i][j];
                if (s < bestv[i]) { bestv[i] = s; besti[i] = code; }
            }
        }
        __syncthreads();   // protect Es/Sq before next chunk's loads
    }

    #pragma unroll
    for (int i = 0; i < 4; ++i) {
        redv[ty][tx*4 + i] = bestv[i];
        redi[ty][tx*4 + i] = besti[i];
    }
    __syncthreads();
    if (tid < 64) {
        float bv = redv[0][tid];
        int   bi = redi[0][tid];
        #pragma unroll
        for (int g = 1; g < 16; ++g) {
            float v = redv[g][tid];
            int ii  = redi[g][tid];
            if (v < bv || (v == bv && ii < bi)) { bv = v; bi = ii; }
        }
        int grow = row0 + tid;
        idx[grow] = bi;
        out_idx[grow] = (float)bi;
        atomicAdd(&counts[bi], 1);
    }
}

// ---------------------------------------------------------------------------
// D = emb @ W_recv + b_recv   [4096,64]x[64,1024] — decoded codebook
__global__ __launch_bounds__(256) void k_dec(const float* __restrict__ embT,
                                             const float* __restrict__ Wr,
                                             const float* __restrict__ br,
                                             float* __restrict__ D) {
    __shared__ float Ek[64][68];    // [dim][code]
    __shared__ float Wt[64][132];   // [dim][col]
    int cb0  = (blockIdx.x & 63) * 64;    // code block
    int col0 = (blockIdx.x >> 6) * 128;   // col block (8 of them)
    int tid = threadIdx.x;
    int tx = tid & 15;    // codes tx*4..+3
    int ty = tid >> 4;    // cols ty*8..+7

    for (int q = tid; q < 1024; q += 256) {
        int c = q >> 4, k4 = q & 15;
        *(float4*)&Ek[c][k4*4] = *(const float4*)&embT[(size_t)c * KC + cb0 + k4*4];
    }
    for (int q = tid; q < 2048; q += 256) {
        int c = q >> 5, k4 = q & 31;
        *(float4*)&Wt[c][k4*4] = *(const float4*)&Wr[(size_t)c * DIN + col0 + k4*4];
    }
    __syncthreads();

    float acc[4][8] = {};
    #pragma unroll 8
    for (int c = 0; c < 64; ++c) {
        float4 av = *(const float4*)&Ek[c][tx*4];
        float4 w0 = *(const float4*)&Wt[c][ty*8];
        float4 w1 = *(const float4*)&Wt[c][ty*8 + 4];
        float a[4] = {av.x, av.y, av.z, av.w};
        float w[8] = {w0.x, w0.y, w0.z, w0.w, w1.x, w1.y, w1.z, w1.w};
        #pragma unroll
        for (int i = 0; i < 4; ++i)
            #pragma unroll
            for (int j = 0; j < 8; ++j)
                acc[i][j] += a[i] * w[j];
    }

    #pragma unroll
    for (int i = 0; i < 4; ++i) {
        int code = cb0 + tx*4 + i;
        float4 o0, o1;
        o0.x = acc[i][0] + br[col0 + ty*8 + 0];
        o0.y = acc[i][1] + br[col0 + ty*8 + 1];
        o0.z = acc[i][2] + br[col0 + ty*8 + 2];
        o0.w = acc[i][3] + br[col0 + ty*8 + 3];
        o1.x = acc[i][4] + br[col0 + ty*8 + 4];
        o1.y = acc[i][5] + br[col0 + ty*8 + 5];
        o1.z = acc[i][6] + br[col0 + ty*8 + 6];
        o1.w = acc[i][7] + br[col0 + ty*8 + 7];
        *(float4*)&D[(size_t)code * DIN + col0 + ty*8]     = o0;
        *(float4*)&D[(size_t)code * DIN + col0 + ty*8 + 4] = o1;
    }
}

// ---------------------------------------------------------------------------
// x[s] = D[idx[s]]  (bias already folded into D)
__global__ __launch_bounds__(256) void k_gather(const float* __restrict__ D,
                                                const int* __restrict__ idx,
                                                float* __restrict__ x) {
    int s = blockIdx.x;
    int code = idx[s];
    const float4* src = (const float4*)&D[(size_t)code * DIN];
    float4* dst = (float4*)&x[(size_t)s * DIN];
    dst[threadIdx.x] = src[threadIdx.x];
}

// ---------------------------------------------------------------------------
// loss partials: sum over rows of ||emb[idx]-z||^2 ; one wave per 32 rows.
__global__ __launch_bounds__(256) void k_loss(const float* __restrict__ z,
                                              const float* __restrict__ emb,
                                              const int* __restrict__ idx,
                                              float* __restrict__ partials) {
    int gw = (blockIdx.x * 256 + threadIdx.x) >> 6;   // 1024 waves
    int lane = threadIdx.x & 63;
    float acc = 0.f;
    for (int r = gw * 32; r < gw * 32 + 32; ++r) {
        int code = idx[r];
        float d = z[(size_t)r * DC + lane] - emb[(size_t)code * DC + lane];
        acc += d * d;
    }
    #pragma unroll
    for (int off = 32; off > 0; off >>= 1) acc += __shfl_down(acc, off);
    if (lane == 0) partials[gw] = acc;
}

// ---------------------------------------------------------------------------
// final: sum partials -> both losses; entropy from counts.
__global__ __launch_bounds__(256) void k_final(const int* __restrict__ counts,
                                               const float* __restrict__ partials,
                                               float* __restrict__ out_sc) {
    __shared__ float red[256];
    int tid = threadIdx.x;

    float lp = 0.f;
    for (int q = tid; q < 1024; q += 256) lp += partials[q];
    red[tid] = lp; __syncthreads();
    for (int s = 128; s > 0; s >>= 1) {
        if (tid < s) red[tid] += red[tid + s];
        __syncthreads();
    }
    float loss = red[0];
    __syncthreads();

    float ep = 0.f;
    for (int k = tid; k < KC; k += 256) {
        int c = counts[k];
        if (c > 0) {
            float p = (float)c / 32768.0f;
            ep += p * logf(p);
        }
    }
    red[tid] = ep; __syncthreads();
    for (int s = 128; s > 0; s >>= 1) {
        if (tid < s) red[tid] += red[tid + s];
        __syncthreads();
    }
    if (tid == 0) {
        out_sc[0] = loss;                                // embedding_loss
        out_sc[1] = loss;                                // commitment_loss (== fwd)
        out_sc[2] = -red[0] * 1.4426950408889634f;       // -sum(p ln p)/ln 2
    }
}

// ---------------------------------------------------------------------------
extern "C" void kernel_launch(void* const* d_in, const int* in_sizes, int n_in,
                              void* d_out, int out_size, void* d_ws, size_t ws_size,
                              hipStream_t stream) {
    (void)in_sizes; (void)n_in; (void)out_size; (void)ws_size;
    const float* input  = (const float*)d_in[0];
    const float* W_send = (const float*)d_in[1];
    const float* b_send = (const float*)d_in[2];
    const float* emb    = (const float*)d_in[3];
    const float* W_recv = (const float*)d_in[4];
    const float* b_recv = (const float*)d_in[5];
    float* out = (float*)d_out;

    char* ws = (char*)d_ws;
    float* z        = (float*)(ws);                    //  8 MB
    float* D        = (float*)(ws + 8388608);          // 16 MB
    float* embT     = (float*)(ws + 25165824);         //  1 MB
    float* sqr      = (float*)(ws + 26214400);         // 16 KB
    int*   idx      = (int*)  (ws + 26230784);         // 128 KB
    int*   counts   = (int*)  (ws + 26361856);         // 16 KB
    float* partials = (float*)(ws + 26378240);         //  4 KB

    float* out_x   = out;                    // 33554432 elems
    float* out_idx = out + 33554432;         // 32768 elems
    float* out_sc  = out + 33587200;         // 3 elems

    hipMemsetAsync(counts, 0, KC * sizeof(int), stream);

    k_transpose_emb<<<64, 256, 0, stream>>>(emb, embT);
    k_sqr<<<16, 256, 0, stream>>>(embT, sqr);
    k_send<<<512, 256, 0, stream>>>(input, W_send, b_send, z);
    k_argmin<<<512, 256, 0, stream>>>(z, embT, sqr, idx, out_idx, counts);
    k_dec<<<512, 256, 0, stream>>>(embT, W_recv, b_recv, D);
    k_gather<<<M_ROWS, 256, 0, stream>>>(D, idx, out_x);
    k_loss<<<256, 256, 0, stream>>>(z, emb, idx, partials);
    k_final<<<1, 256, 0, stream>>>(counts, partials, out_sc);
}

// Round 2
// 316.171 us; speedup vs baseline: 1.2437x; 1.2437x over previous
//
#include <hip/hip_runtime.h>

#define M_ROWS 32768   // B*S
#define DIN 1024
#define DC 64
#define KC 4096

// ---------------------------------------------------------------------------
// Transpose emb [KC][DC] -> embT [DC][KC], fused with sqr[k] = ||emb_k||^2.
__global__ __launch_bounds__(256) void k_prep(const float* __restrict__ emb,
                                              float* __restrict__ embT,
                                              float* __restrict__ sqr) {
    __shared__ float t[64][68];
    int k0 = blockIdx.x * 64;
    int tid = threadIdx.x;
    for (int q = tid; q < 1024; q += 256) {
        int r = q >> 4, c4 = q & 15;
        float4 v = *(const float4*)&emb[(size_t)(k0 + r) * DC + c4 * 4];
        t[r][c4*4+0] = v.x; t[r][c4*4+1] = v.y; t[r][c4*4+2] = v.z; t[r][c4*4+3] = v.w;
    }
    __syncthreads();
    for (int q = tid; q < 1024; q += 256) {
        int c = q >> 4, k4 = q & 15;
        float4 v;
        v.x = t[k4*4+0][c]; v.y = t[k4*4+1][c]; v.z = t[k4*4+2][c]; v.w = t[k4*4+3][c];
        *(float4*)&embT[(size_t)c * KC + k0 + k4*4] = v;
    }
    if (tid < 64) {
        float s = 0.f;
        #pragma unroll
        for (int c = 0; c < 64; ++c) { float e = t[tid][c]; s += e * e; }
        sqr[k0 + tid] = s;
    }
}

// ---------------------------------------------------------------------------
// z = input @ W_send + b_send   [32768,1024]x[1024,64]
__global__ __launch_bounds__(256) void k_send(const float* __restrict__ in,
                                              const float* __restrict__ Ws,
                                              const float* __restrict__ bs,
                                              float* __restrict__ z) {
    __shared__ float As[32][68];   // [k][row]
    __shared__ float Bs[32][64];   // [k][col]
    int row0 = blockIdx.x * 64;
    int tid = threadIdx.x;
    int tx = tid & 15;    // rows tx*4..+3
    int ty = tid >> 4;    // cols ty*4..+3
    float bias[4];
    #pragma unroll
    for (int j = 0; j < 4; ++j) bias[j] = bs[ty*4 + j];

    float acc[4][4] = {};
    for (int k0 = 0; k0 < DIN; k0 += 32) {
        for (int q = tid; q < 512; q += 256) {
            int r = q >> 3, c4 = q & 7;
            float4 v = *(const float4*)&in[(size_t)(row0 + r) * DIN + k0 + c4*4];
            As[c4*4+0][r] = v.x; As[c4*4+1][r] = v.y;
            As[c4*4+2][r] = v.z; As[c4*4+3][r] = v.w;
        }
        for (int q = tid; q < 512; q += 256) {
            int kr = q >> 4, c4 = q & 15;
            *(float4*)&Bs[kr][c4*4] = *(const float4*)&Ws[(size_t)(k0 + kr) * DC + c4*4];
        }
        __syncthreads();
        #pragma unroll
        for (int k = 0; k < 32; ++k) {
            float4 av = *(const float4*)&As[k][tx*4];
            float4 bv = *(const float4*)&Bs[k][ty*4];
            float a[4] = {av.x, av.y, av.z, av.w};
            float b[4] = {bv.x, bv.y, bv.z, bv.w};
            #pragma unroll
            for (int i = 0; i < 4; ++i)
                #pragma unroll
                for (int j = 0; j < 4; ++j)
                    acc[i][j] += a[i] * b[j];
        }
        __syncthreads();
    }
    #pragma unroll
    for (int i = 0; i < 4; ++i) {
        int r = row0 + tx*4 + i;
        float4 o;
        o.x = acc[i][0] + bias[0];
        o.y = acc[i][1] + bias[1];
        o.z = acc[i][2] + bias[2];
        o.w = acc[i][3] + bias[3];
        *(float4*)&z[(size_t)r * DC + ty*4] = o;
    }
}

// ---------------------------------------------------------------------------
// argmin_k  sqr[k] - 2*<z_row, emb_k>
// 512 threads; block tile 128 rows x 256 codes/chunk; thread tile 8x8.
// LDS: Zs[64][136] (split row layout) | Es[64][260] | Sq[256]  = 102.4 KB
__global__ __launch_bounds__(512, 2) void k_argmin(const float* __restrict__ z,
                                                   const float* __restrict__ embT,
                                                   const float* __restrict__ sqr,
                                                   int* __restrict__ idx,
                                                   float* __restrict__ out_idx,
                                                   int* __restrict__ counts) {
    __shared__ float smem[25600];
    float* Zs = smem;                       // 64*136 = 8704
    float* Es = smem + 8704;                // 64*260 = 16640
    float* Sq = smem + 25344;               // 256

    int tid = threadIdx.x;
    int row0 = blockIdx.x * 128;
    int tx = tid & 15;        // row group: rows tx*8..+7
    int ty = tid >> 4;        // code group (0..31): codes ty*8..+7 within chunk

    // stage z tile transposed, rows in split layout:
    // Zs[c][f*64 + (r>>3)*4 + (r&3)] = z[row0+r][c],  f=(r>>2)&1
    #pragma unroll
    for (int it = 0; it < 4; ++it) {
        int q = it * 512 + tid;              // 2048 float4s
        int r = q >> 4, c4 = q & 15;
        float4 v = *(const float4*)&z[(size_t)(row0 + r) * DC + c4*4];
        int phys = ((r >> 2) & 1) * 64 + ((r >> 3) << 2) + (r & 3);
        Zs[(c4*4+0)*136 + phys] = v.x;
        Zs[(c4*4+1)*136 + phys] = v.y;
        Zs[(c4*4+2)*136 + phys] = v.z;
        Zs[(c4*4+3)*136 + phys] = v.w;
    }

    float bestv[8]; int besti[8];
    #pragma unroll
    for (int i = 0; i < 8; ++i) { bestv[i] = 3.402823466e38f; besti[i] = 0; }

    const float* zp = Zs + tx*4;
    const float* ep = Es + ty*8;

    for (int ch = 0; ch < 16; ++ch) {
        int code0 = ch * 256;
        #pragma unroll
        for (int it = 0; it < 8; ++it) {
            int q = it * 512 + tid;          // 4096 float4s
            int c = q >> 6, k4 = q & 63;
            *(float4*)&Es[c*260 + k4*4] =
                *(const float4*)&embT[(size_t)c * KC + code0 + k4*4];
        }
        if (tid < 256) Sq[tid] = sqr[code0 + tid];
        __syncthreads();

        float dot[8][8] = {};
        #pragma unroll 4
        for (int c = 0; c < 64; ++c) {
            float4 z0 = *(const float4*)(zp + c*136);
            float4 z1 = *(const float4*)(zp + c*136 + 64);
            float4 e0 = *(const float4*)(ep + c*260);
            float4 e1 = *(const float4*)(ep + c*260 + 4);
            float zz[8] = {z0.x,z0.y,z0.z,z0.w, z1.x,z1.y,z1.z,z1.w};
            float ee[8] = {e0.x,e0.y,e0.z,e0.w, e1.x,e1.y,e1.z,e1.w};
            #pragma unroll
            for (int i = 0; i < 8; ++i)
                #pragma unroll
                for (int j = 0; j < 8; ++j)
                    dot[i][j] += zz[i] * ee[j];
        }

        #pragma unroll
        for (int j = 0; j < 8; ++j) {
            float sq = Sq[ty*8 + j];
            int code = code0 + ty*8 + j;
            #pragma unroll
            for (int i = 0; i < 8; ++i) {
                float s = sq - 2.0f * dot[i][j];
                if (s < bestv[i]) { bestv[i] = s; besti[i] = code; }
            }
        }
        __syncthreads();
    }

    // cross-thread reduction over the 32 code-groups (reuse Es region)
    float* redv = Es;
    int*   redi = (int*)(Es + 32*132);
    #pragma unroll
    for (int i = 0; i < 8; ++i) {
        redv[ty*132 + tx*8 + i] = bestv[i];
        redi[ty*132 + tx*8 + i] = besti[i];
    }
    __syncthreads();
    if (tid < 128) {
        float bv = redv[tid]; int bi = redi[tid];
        #pragma unroll
        for (int g = 1; g < 32; ++g) {
            float v = redv[g*132 + tid]; int ii = redi[g*132 + tid];
            if (v < bv || (v == bv && ii < bi)) { bv = v; bi = ii; }
        }
        int grow = row0 + tid;
        idx[grow] = bi;
        out_idx[grow] = (float)bi;
        atomicAdd(&counts[bi], 1);
    }
}

// ---------------------------------------------------------------------------
// D = emb @ W_recv + b_recv   [4096,64]x[64,1024]
__global__ __launch_bounds__(256) void k_dec(const float* __restrict__ embT,
                                             const float* __restrict__ Wr,
                                             const float* __restrict__ br,
                                             float* __restrict__ D) {
    __shared__ float Ek[64][68];
    __shared__ float Wt[64][132];
    int cb0  = (blockIdx.x & 63) * 64;
    int col0 = (blockIdx.x >> 6) * 128;
    int tid = threadIdx.x;
    int tx = tid & 15;
    int ty = tid >> 4;

    for (int q = tid; q < 1024; q += 256) {
        int c = q >> 4, k4 = q & 15;
        *(float4*)&Ek[c][k4*4] = *(const float4*)&embT[(size_t)c * KC + cb0 + k4*4];
    }
    for (int q = tid; q < 2048; q += 256) {
        int c = q >> 5, k4 = q & 31;
        *(float4*)&Wt[c][k4*4] = *(const float4*)&Wr[(size_t)c * DIN + col0 + k4*4];
    }
    __syncthreads();

    float acc[4][8] = {};
    #pragma unroll 8
    for (int c = 0; c < 64; ++c) {
        float4 av = *(const float4*)&Ek[c][tx*4];
        float4 w0 = *(const float4*)&Wt[c][ty*8];
        float4 w1 = *(const float4*)&Wt[c][ty*8 + 4];
        float a[4] = {av.x, av.y, av.z, av.w};
        float w[8] = {w0.x, w0.y, w0.z, w0.w, w1.x, w1.y, w1.z, w1.w};
        #pragma unroll
        for (int i = 0; i < 4; ++i)
            #pragma unroll
            for (int j = 0; j < 8; ++j)
                acc[i][j] += a[i] * w[j];
    }

    #pragma unroll
    for (int i = 0; i < 4; ++i) {
        int code = cb0 + tx*4 + i;
        float4 o0, o1;
        o0.x = acc[i][0] + br[col0 + ty*8 + 0];
        o0.y = acc[i][1] + br[col0 + ty*8 + 1];
        o0.z = acc[i][2] + br[col0 + ty*8 + 2];
        o0.w = acc[i][3] + br[col0 + ty*8 + 3];
        o1.x = acc[i][4] + br[col0 + ty*8 + 4];
        o1.y = acc[i][5] + br[col0 + ty*8 + 5];
        o1.z = acc[i][6] + br[col0 + ty*8 + 6];
        o1.w = acc[i][7] + br[col0 + ty*8 + 7];
        *(float4*)&D[(size_t)code * DIN + col0 + ty*8]     = o0;
        *(float4*)&D[(size_t)code * DIN + col0 + ty*8 + 4] = o1;
    }
}

// ---------------------------------------------------------------------------
// x[s] = D[idx[s]]  grid-stride over 2M float4s
__global__ __launch_bounds__(256) void k_gather(const float* __restrict__ D,
                                                const int* __restrict__ idx,
                                                float* __restrict__ x) {
    int g = blockIdx.x * 256 + threadIdx.x;
    #pragma unroll
    for (int it = 0; it < 4; ++it) {
        int f = g + it * 524288;
        int row = f >> 6, c = f & 63;
        int code = idx[row];
        *(float4*)&x[(size_t)row * DIN + c*4] =
            *(const float4*)&D[(size_t)code * DIN + c*4];
    }
}

// ---------------------------------------------------------------------------
__global__ __launch_bounds__(256) void k_loss(const float* __restrict__ z,
                                              const float* __restrict__ emb,
                                              const int* __restrict__ idx,
                                              float* __restrict__ partials) {
    int gw = (blockIdx.x * 256 + threadIdx.x) >> 6;
    int lane = threadIdx.x & 63;
    float acc = 0.f;
    for (int r = gw * 32; r < gw * 32 + 32; ++r) {
        int code = idx[r];
        float d = z[(size_t)r * DC + lane] - emb[(size_t)code * DC + lane];
        acc += d * d;
    }
    #pragma unroll
    for (int off = 32; off > 0; off >>= 1) acc += __shfl_down(acc, off);
    if (lane == 0) partials[gw] = acc;
}

// ---------------------------------------------------------------------------
__global__ __launch_bounds__(256) void k_final(const int* __restrict__ counts,
                                               const float* __restrict__ partials,
                                               float* __restrict__ out_sc) {
    __shared__ float red[256];
    int tid = threadIdx.x;

    float lp = 0.f;
    for (int q = tid; q < 1024; q += 256) lp += partials[q];
    red[tid] = lp; __syncthreads();
    for (int s = 128; s > 0; s >>= 1) {
        if (tid < s) red[tid] += red[tid + s];
        __syncthreads();
    }
    float loss = red[0];
    __syncthreads();

    float ep = 0.f;
    for (int k = tid; k < KC; k += 256) {
        int c = counts[k];
        if (c > 0) {
            float p = (float)c / 32768.0f;
            ep += p * logf(p);
        }
    }
    red[tid] = ep; __syncthreads();
    for (int s = 128; s > 0; s >>= 1) {
        if (tid < s) red[tid] += red[tid + s];
        __syncthreads();
    }
    if (tid == 0) {
        out_sc[0] = loss;
        out_sc[1] = loss;
        out_sc[2] = -red[0] * 1.4426950408889634f;
    }
}

// ---------------------------------------------------------------------------
extern "C" void kernel_launch(void* const* d_in, const int* in_sizes, int n_in,
                              void* d_out, int out_size, void* d_ws, size_t ws_size,
                              hipStream_t stream) {
    (void)in_sizes; (void)n_in; (void)out_size; (void)ws_size;
    const float* input  = (const float*)d_in[0];
    const float* W_send = (const float*)d_in[1];
    const float* b_send = (const float*)d_in[2];
    const float* emb    = (const float*)d_in[3];
    const float* W_recv = (const float*)d_in[4];
    const float* b_recv = (const float*)d_in[5];
    float* out = (float*)d_out;

    char* ws = (char*)d_ws;
    float* z        = (float*)(ws);                    //  8 MB
    float* D        = (float*)(ws + 8388608);          // 16 MB
    float* embT     = (float*)(ws + 25165824);         //  1 MB
    float* sqr      = (float*)(ws + 26214400);         // 16 KB
    int*   idx      = (int*)  (ws + 26230784);         // 128 KB
    int*   counts   = (int*)  (ws + 26361856);         // 16 KB
    float* partials = (float*)(ws + 26378240);         //  4 KB

    float* out_x   = out;                    // 33554432 elems
    float* out_idx = out + 33554432;         // 32768 elems
    float* out_sc  = out + 33587200;         // 3 elems

    hipMemsetAsync(counts, 0, KC * sizeof(int), stream);

    k_prep<<<64, 256, 0, stream>>>(emb, embT, sqr);
    k_send<<<512, 256, 0, stream>>>(input, W_send, b_send, z);
    k_argmin<<<256, 512, 0, stream>>>(z, embT, sqr, idx, out_idx, counts);
    k_dec<<<512, 256, 0, stream>>>(embT, W_recv, b_recv, D);
    k_gather<<<2048, 256, 0, stream>>>(D, idx, out_x);
    k_loss<<<256, 256, 0, stream>>>(z, emb, idx, partials);
    k_final<<<1, 256, 0, stream>>>(counts, partials, out_sc);
}

// Round 4
// 207.489 us; speedup vs baseline: 1.8952x; 1.5238x over previous
//
#include <hip/hip_runtime.h>

#define DIN 1024
#define DC 64
#define KC 4096

typedef _Float16 f16x8 __attribute__((ext_vector_type(8)));
typedef _Float16 f16x4 __attribute__((ext_vector_type(4)));
typedef float f32x4 __attribute__((ext_vector_type(4)));

__device__ __forceinline__ void gll16(const void* g, void* l) {
    __builtin_amdgcn_global_load_lds(
        (const __attribute__((address_space(1))) unsigned int*)g,
        (__attribute__((address_space(3))) unsigned int*)l, 16, 0, 0);
}

// ---------------------------------------------------------------------------
// E_ext [4096][192] f16 = [eh | e2 | eh], e2 = (e - eh)*1024 ; sqr[k] fp32.
__global__ __launch_bounds__(256) void k_prep(const float* __restrict__ emb,
                                              _Float16* __restrict__ Ee,
                                              float* __restrict__ sqr) {
    int code = blockIdx.x * 4 + (threadIdx.x >> 6);
    int lane = threadIdx.x & 63;
    float v = emb[(size_t)code * DC + lane];
    _Float16 eh = (_Float16)v;
    _Float16 e2 = (_Float16)((v - (float)eh) * 1024.0f);
    _Float16* row = Ee + (size_t)code * 192;
    row[lane]       = eh;   // slot0: pairs with z2
    row[64 + lane]  = e2;   // slot1: pairs with zh
    row[128 + lane] = eh;   // slot2: pairs with zh
    float s = v * v;
    #pragma unroll
    for (int m = 1; m < 64; m <<= 1) s += __shfl_xor(s, m);
    if (lane == 0) sqr[code] = s;
}

// ---------------------------------------------------------------------------
// z = input @ W_send + b_send ; emit Z_ext [32768][192] f16 = [z2 | zh | zh]
__global__ __launch_bounds__(256) void k_send(const float* __restrict__ in,
                                              const float* __restrict__ Ws,
                                              const float* __restrict__ bs,
                                              _Float16* __restrict__ Ze) {
    __shared__ float As[32][68];   // [k][row]
    __shared__ float Bs[32][64];   // [k][col]
    int row0 = blockIdx.x * 64;
    int tid = threadIdx.x;
    int tx = tid & 15;    // rows tx*4..+3
    int ty = tid >> 4;    // cols ty*4..+3
    float bias[4];
    #pragma unroll
    for (int j = 0; j < 4; ++j) bias[j] = bs[ty*4 + j];

    float acc[4][4] = {};
    for (int k0 = 0; k0 < DIN; k0 += 32) {
        for (int q = tid; q < 512; q += 256) {
            int r = q >> 3, c4 = q & 7;
            float4 v = *(const float4*)&in[(size_t)(row0 + r) * DIN + k0 + c4*4];
            As[c4*4+0][r] = v.x; As[c4*4+1][r] = v.y;
            As[c4*4+2][r] = v.z; As[c4*4+3][r] = v.w;
        }
        for (int q = tid; q < 512; q += 256) {
            int kr = q >> 4, c4 = q & 15;
            *(float4*)&Bs[kr][c4*4] = *(const float4*)&Ws[(size_t)(k0 + kr) * DC + c4*4];
        }
        __syncthreads();
        #pragma unroll
        for (int k = 0; k < 32; ++k) {
            float4 av = *(const float4*)&As[k][tx*4];
            float4 bv = *(const float4*)&Bs[k][ty*4];
            float a[4] = {av.x, av.y, av.z, av.w};
            float b[4] = {bv.x, bv.y, bv.z, bv.w};
            #pragma unroll
            for (int i = 0; i < 4; ++i)
                #pragma unroll
                for (int j = 0; j < 4; ++j)
                    acc[i][j] += a[i] * b[j];
        }
        __syncthreads();
    }
    #pragma unroll
    for (int i = 0; i < 4; ++i) {
        int r = row0 + tx*4 + i;
        _Float16* zr = Ze + (size_t)r * 192;
        f16x4 h, l2;
        #pragma unroll
        for (int j = 0; j < 4; ++j) {
            float v = acc[i][j] + bias[j];
            _Float16 zh = (_Float16)v;
            h[j] = zh;
            l2[j] = (_Float16)((v - (float)zh) * 1024.0f);
        }
        *(f16x4*)(zr + ty*4)       = l2;   // slot0: z2
        *(f16x4*)(zr + 64 + ty*4)  = h;    // slot1: zh
        *(f16x4*)(zr + 128 + ty*4) = h;    // slot2: zh
    }
}

// ---------------------------------------------------------------------------
// MFMA score kernel: A = E codes (M), B = Z rows (N), K = 192 in 3 chunks.
// Chunks staged: kc0->buf0, kc1->buf1, kc2->buf0.  compute() takes the
// BUFFER index (round-3 bug: passed chunk index 2 -> OOB LDS read).
__global__ __launch_bounds__(512, 2) void k_score(const _Float16* __restrict__ Ee,
                                                  const _Float16* __restrict__ Ze,
                                                  const float* __restrict__ sqr,
                                                  float* __restrict__ pv,
                                                  int* __restrict__ pi) {
    __shared__ char smem[131072];
    const int tid = threadIdx.x;
    const int bx = blockIdx.x;
    const int cb = bx & 15;          // code-chunk of 256
    const int rb = bx >> 4;          // row-block of 256
    const int wid = tid >> 6, lane = tid & 63;
    const int c15 = lane & 15, g = lane >> 4;
    const int wm = wid >> 2, wn = wid & 3;

    const char* EeB = (const char*)(Ee + (size_t)cb * 256 * 192);
    const char* ZeB = (const char*)(Ze + (size_t)rb * 256 * 192);

    f32x4 acc[8][4];
    const f32x4 zz4 = {0.f, 0.f, 0.f, 0.f};
    #pragma unroll
    for (int mf = 0; mf < 8; ++mf)
        #pragma unroll
        for (int nf = 0; nf < 4; ++nf) acc[mf][nf] = zz4;

    int abase[8], aswz[8];
    #pragma unroll
    for (int mf = 0; mf < 8; ++mf) {
        int row = wm*128 + mf*16 + c15;
        abase[mf] = row * 128;
        aswz[mf] = (row & 7) << 4;
    }
    int bbase[4], bswz[4];
    #pragma unroll
    for (int nf = 0; nf < 4; ++nf) {
        int row = wn*64 + nf*16 + c15;
        bbase[nf] = row * 128;
        bswz[nf] = (row & 7) << 4;
    }
    const int g16 = g * 16;

    // stage chunk kc (64 k-slots = 128 B/row) into buffer b.
    // LDS linear dest; swizzle applied on the per-lane GLOBAL source (m173).
    auto stage = [&](int kc, int b) {
        char* lbase = smem + b * 65536;
        #pragma unroll
        for (int r = 0; r < 4; ++r) {              // A: 256 code rows, 32 KB
            int p = r * 8192 + wid * 1024 + lane * 16;
            int row = p >> 7, off = p & 127;
            int soff = off ^ ((row & 7) << 4);
            gll16(EeB + (size_t)row * 384 + kc * 128 + soff,
                  lbase + r * 8192 + wid * 1024);
        }
        #pragma unroll
        for (int r = 0; r < 4; ++r) {              // B: 256 z rows, 32 KB
            int p = r * 8192 + wid * 1024 + lane * 16;
            int row = p >> 7, off = p & 127;
            int soff = off ^ ((row & 7) << 4);
            gll16(ZeB + (size_t)row * 384 + kc * 128 + soff,
                  lbase + 32768 + r * 8192 + wid * 1024);
        }
    };

    auto compute = [&](int b) {   // b = BUFFER index (0 or 1)
        const char* BA = smem + b * 65536;
        const char* BB = BA + 32768;
        #pragma unroll
        for (int s = 0; s < 2; ++s) {
            const int koff = s * 64 + g16;
            f16x8 bf[4];
            #pragma unroll
            for (int nf = 0; nf < 4; ++nf)
                bf[nf] = *(const f16x8*)(BB + bbase[nf] + (koff ^ bswz[nf]));
            #pragma unroll
            for (int mf = 0; mf < 8; ++mf) {
                f16x8 af = *(const f16x8*)(BA + abase[mf] + (koff ^ aswz[mf]));
                #pragma unroll
                for (int nf = 0; nf < 4; ++nf)
                    acc[mf][nf] = __builtin_amdgcn_mfma_f32_16x16x32_f16(
                        af, bf[nf], acc[mf][nf], 0, 0, 0);
            }
        }
    };

    stage(0, 0);
    __syncthreads();               // buf0 (chunk0) ready
    stage(1, 1);
    compute(0);                    // chunk0: z2*eh   (buf0)
    __syncthreads();               // buf1 (chunk1) ready; buf0 free
    stage(2, 0);
    compute(1);                    // chunk1: + zh*e2 (buf1)
    #pragma unroll
    for (int mf = 0; mf < 8; ++mf) // fold: *= 2^-10
        #pragma unroll
        for (int nf = 0; nf < 4; ++nf)
            acc[mf][nf] *= 0.0009765625f;
    __syncthreads();               // buf0 (chunk2) ready
    compute(0);                    // chunk2: + zh*eh (buf0!  was the bug)
    __syncthreads();

    // ---- epilogue: score + argmin ----
    f32x4 sqv[8];
    const float* sq = sqr + cb * 256 + wm * 128 + g * 4;
    #pragma unroll
    for (int mf = 0; mf < 8; ++mf)
        sqv[mf] = *(const f32x4*)(sq + mf * 16);

    float* redv = (float*)smem;
    int* redi = (int*)(smem + 2048);

    #pragma unroll
    for (int nf = 0; nf < 4; ++nf) {
        float bv = 3.402823466e38f;
        int bi = 0;
        #pragma unroll
        for (int mf = 0; mf < 8; ++mf)
            #pragma unroll
            for (int r2 = 0; r2 < 4; ++r2) {
                float v = sqv[mf][r2] - 2.0f * acc[mf][nf][r2];
                // codes ascend with (mf,r2) within a lane: strict < = first-min
                if (v < bv) { bv = v; bi = cb*256 + wm*128 + mf*16 + g*4 + r2; }
            }
        #pragma unroll
        for (int m = 16; m <= 32; m <<= 1) {
            float ov = __shfl_xor(bv, m);
            int oi = __shfl_xor(bi, m);
            if (ov < bv || (ov == bv && oi < bi)) { bv = ov; bi = oi; }
        }
        if (g == 0) {
            int rl = wn * 64 + nf * 16 + c15;
            redv[wm * 256 + rl] = bv;
            redi[wm * 256 + rl] = bi;
        }
    }
    __syncthreads();
    if (tid < 256) {
        float v0 = redv[tid]; int i0 = redi[tid];
        float v1 = redv[256 + tid]; int i1 = redi[256 + tid];
        if (v1 < v0 || (v1 == v0 && i1 < i0)) { v0 = v1; i0 = i1; }
        size_t o = (size_t)cb * 32768 + (size_t)rb * 256 + tid;
        pv[o] = v0;
        pi[o] = i0;
    }
}

// ---------------------------------------------------------------------------
// final argmin across the 16 code-chunks; idx, out_idx, counts.
__global__ __launch_bounds__(256) void k_idxfinal(const float* __restrict__ pv,
                                                  const int* __restrict__ pi,
                                                  int* __restrict__ idx,
                                                  float* __restrict__ out_idx,
                                                  int* __restrict__ counts) {
    int r = blockIdx.x * 256 + threadIdx.x;
    float bv = pv[r]; int bi = pi[r];
    #pragma unroll
    for (int c = 1; c < 16; ++c) {
        float v = pv[(size_t)c * 32768 + r];
        int i2 = pi[(size_t)c * 32768 + r];
        if (v < bv || (v == bv && i2 < bi)) { bv = v; bi = i2; }
    }
    idx[r] = bi;
    out_idx[r] = (float)bi;
    atomicAdd(&counts[bi], 1);
}

// ---------------------------------------------------------------------------
// loss partials from Z_ext (z = zh + z2/1024) and emb.
__global__ __launch_bounds__(256) void k_loss(const _Float16* __restrict__ Ze,
                                              const float* __restrict__ emb,
                                              const int* __restrict__ idx,
                                              float* __restrict__ partials) {
    int gw = (blockIdx.x * 256 + threadIdx.x) >> 6;
    int lane = threadIdx.x & 63;
    float acc = 0.f;
    for (int r = gw * 32; r < gw * 32 + 32; ++r) {
        int code = idx[r];
        const _Float16* zr = Ze + (size_t)r * 192;
        float z = (float)zr[64 + lane] + (float)zr[lane] * 0.0009765625f;
        float d = z - emb[(size_t)code * DC + lane];
        acc += d * d;
    }
    #pragma unroll
    for (int off = 32; off > 0; off >>= 1) acc += __shfl_down(acc, off);
    if (lane == 0) partials[gw] = acc;
}

// ---------------------------------------------------------------------------
// D = emb @ W_recv + b_recv   [4096,64]x[64,1024]
__global__ __launch_bounds__(256) void k_dec(const float* __restrict__ emb,
                                             const float* __restrict__ Wr,
                                             const float* __restrict__ br,
                                             float* __restrict__ D) {
    __shared__ float Ek[64][68];    // [dim][code]
    __shared__ float Wt[64][132];   // [dim][col]
    int cb0  = (blockIdx.x & 63) * 64;
    int col0 = (blockIdx.x >> 6) * 128;
    int tid = threadIdx.x;
    int tx = tid & 15;
    int ty = tid >> 4;

    for (int q = tid; q < 1024; q += 256) {
        int r = q >> 4, c4 = q & 15;
        float4 v = *(const float4*)&emb[(size_t)(cb0 + r) * DC + c4*4];
        Ek[c4*4+0][r] = v.x; Ek[c4*4+1][r] = v.y;
        Ek[c4*4+2][r] = v.z; Ek[c4*4+3][r] = v.w;
    }
    for (int q = tid; q < 2048; q += 256) {
        int c = q >> 5, k4 = q & 31;
        *(float4*)&Wt[c][k4*4] = *(const float4*)&Wr[(size_t)c * DIN + col0 + k4*4];
    }
    __syncthreads();

    float acc[4][8] = {};
    #pragma unroll 8
    for (int c = 0; c < 64; ++c) {
        float4 av = *(const float4*)&Ek[c][tx*4];
        float4 w0 = *(const float4*)&Wt[c][ty*8];
        float4 w1 = *(const float4*)&Wt[c][ty*8 + 4];
        float a[4] = {av.x, av.y, av.z, av.w};
        float w[8] = {w0.x, w0.y, w0.z, w0.w, w1.x, w1.y, w1.z, w1.w};
        #pragma unroll
        for (int i = 0; i < 4; ++i)
            #pragma unroll
            for (int j = 0; j < 8; ++j)
                acc[i][j] += a[i] * w[j];
    }

    #pragma unroll
    for (int i = 0; i < 4; ++i) {
        int code = cb0 + tx*4 + i;
        float4 o0, o1;
        o0.x = acc[i][0] + br[col0 + ty*8 + 0];
        o0.y = acc[i][1] + br[col0 + ty*8 + 1];
        o0.z = acc[i][2] + br[col0 + ty*8 + 2];
        o0.w = acc[i][3] + br[col0 + ty*8 + 3];
        o1.x = acc[i][4] + br[col0 + ty*8 + 4];
        o1.y = acc[i][5] + br[col0 + ty*8 + 5];
        o1.z = acc[i][6] + br[col0 + ty*8 + 6];
        o1.w = acc[i][7] + br[col0 + ty*8 + 7];
        *(float4*)&D[(size_t)code * DIN + col0 + ty*8]     = o0;
        *(float4*)&D[(size_t)code * DIN + col0 + ty*8 + 4] = o1;
    }
}

// ---------------------------------------------------------------------------
__global__ __launch_bounds__(256) void k_gather(const float* __restrict__ D,
                                                const int* __restrict__ idx,
                                                float* __restrict__ x) {
    int gidx = blockIdx.x * 256 + threadIdx.x;
    #pragma unroll
    for (int it = 0; it < 4; ++it) {
        int f = gidx + it * 524288;
        int row = f >> 6, c = f & 63;
        int code = idx[row];
        *(float4*)&x[(size_t)row * DIN + c*4] =
            *(const float4*)&D[(size_t)code * DIN + c*4];
    }
}

// ---------------------------------------------------------------------------
__global__ __launch_bounds__(256) void k_final(const int* __restrict__ counts,
                                               const float* __restrict__ partials,
                                               float* __restrict__ out_sc) {
    __shared__ float red[256];
    int tid = threadIdx.x;

    float lp = 0.f;
    for (int q = tid; q < 1024; q += 256) lp += partials[q];
    red[tid] = lp; __syncthreads();
    for (int s = 128; s > 0; s >>= 1) {
        if (tid < s) red[tid] += red[tid + s];
        __syncthreads();
    }
    float loss = red[0];
    __syncthreads();

    float ep = 0.f;
    for (int k = tid; k < KC; k += 256) {
        int c = counts[k];
        if (c > 0) {
            float p = (float)c / 32768.0f;
            ep += p * logf(p);
        }
    }
    red[tid] = ep; __syncthreads();
    for (int s = 128; s > 0; s >>= 1) {
        if (tid < s) red[tid] += red[tid + s];
        __syncthreads();
    }
    if (tid == 0) {
        out_sc[0] = loss;
        out_sc[1] = loss;
        out_sc[2] = -red[0] * 1.4426950408889634f;
    }
}

// ---------------------------------------------------------------------------
extern "C" void kernel_launch(void* const* d_in, const int* in_sizes, int n_in,
                              void* d_out, int out_size, void* d_ws, size_t ws_size,
                              hipStream_t stream) {
    (void)in_sizes; (void)n_in; (void)out_size; (void)ws_size;
    const float* input  = (const float*)d_in[0];
    const float* W_send = (const float*)d_in[1];
    const float* b_send = (const float*)d_in[2];
    const float* emb    = (const float*)d_in[3];
    const float* W_recv = (const float*)d_in[4];
    const float* b_recv = (const float*)d_in[5];
    float* out = (float*)d_out;

    char* ws = (char*)d_ws;
    _Float16* Ze  = (_Float16*)(ws);                  // 12.6 MB  [32768][192]
    float*    D   = (float*)(ws);                     // 16.8 MB — aliases Ze (Ze dead before k_dec)
    float*    pvb = (float*)(ws + 16777216);          //  2 MB
    int*      pib = (int*)  (ws + 18874368);          //  2 MB
    _Float16* Ee  = (_Float16*)(ws + 20971520);       //  1.5 MB [4096][192]
    float*    sqr = (float*)(ws + 22544384);          // 16 KB
    int*      idx = (int*)  (ws + 22560768);          // 128 KB
    int*   counts = (int*)  (ws + 22691840);          // 16 KB
    float* lpart  = (float*)(ws + 22708224);          //  4 KB

    float* out_x   = out;                    // 33554432
    float* out_idx = out + 33554432;         // 32768
    float* out_sc  = out + 33587200;         // 3

    hipMemsetAsync(counts, 0, KC * sizeof(int), stream);

    k_prep<<<1024, 256, 0, stream>>>(emb, Ee, sqr);
    k_send<<<512, 256, 0, stream>>>(input, W_send, b_send, Ze);
    k_score<<<2048, 512, 0, stream>>>(Ee, Ze, sqr, pvb, pib);
    k_idxfinal<<<128, 256, 0, stream>>>(pvb, pib, idx, out_idx, counts);
    k_loss<<<256, 256, 0, stream>>>(Ze, emb, idx, lpart);   // before k_dec (Ze alias)
    k_dec<<<512, 256, 0, stream>>>(emb, W_recv, b_recv, D);
    k_gather<<<2048, 256, 0, stream>>>(D, idx, out_x);
    k_final<<<1, 256, 0, stream>>>(counts, lpart, out_sc);
}

// Round 5
// 157.029 us; speedup vs baseline: 2.5042x; 1.3213x over previous
//
#include <hip/hip_runtime.h>

#define DIN 1024
#define DC 64
#define KC 4096

typedef _Float16 f16x8 __attribute__((ext_vector_type(8)));
typedef _Float16 f16x4 __attribute__((ext_vector_type(4)));
typedef float f32x4 __attribute__((ext_vector_type(4)));

__device__ __forceinline__ void gll16(const void* g, void* l) {
    __builtin_amdgcn_global_load_lds(
        (const __attribute__((address_space(1))) unsigned int*)g,
        (__attribute__((address_space(3))) unsigned int*)l, 16, 0, 0);
}

// ---------------------------------------------------------------------------
// E_ext [4096][192] f16 = [eh | e2 | eh], e2 = (e - eh)*1024 ; sqr[k] fp32.
__global__ __launch_bounds__(256) void k_prep(const float* __restrict__ emb,
                                              _Float16* __restrict__ Ee,
                                              float* __restrict__ sqr) {
    int code = blockIdx.x * 4 + (threadIdx.x >> 6);
    int lane = threadIdx.x & 63;
    float v = emb[(size_t)code * DC + lane];
    _Float16 eh = (_Float16)v;
    _Float16 e2 = (_Float16)((v - (float)eh) * 1024.0f);
    _Float16* row = Ee + (size_t)code * 192;
    row[lane]       = eh;   // slot0: pairs with z2
    row[64 + lane]  = e2;   // slot1: pairs with zh
    row[128 + lane] = eh;   // slot2: pairs with zh
    float s = v * v;
    #pragma unroll
    for (int m = 1; m < 64; m <<= 1) s += __shfl_xor(s, m);
    if (lane == 0) sqr[code] = s;
}

// ---------------------------------------------------------------------------
// W_send [1024][64] fp32 -> Wh/Wl [64][1024] f16 (transposed, split)
__global__ __launch_bounds__(256) void k_prepw(const float* __restrict__ Ws,
                                               _Float16* __restrict__ Wh,
                                               _Float16* __restrict__ Wl) {
    int k0 = blockIdx.x * 64;   // 16 blocks
    int tid = threadIdx.x;
    #pragma unroll
    for (int it = 0; it < 16; ++it) {
        int q = it * 256 + tid;          // 4096 = 64c x 64k
        int c = q >> 6, kl = q & 63;
        float v = Ws[(size_t)(k0 + kl) * 64 + c];
        _Float16 h = (_Float16)v;
        _Float16 l = (_Float16)((v - (float)h) * 1024.0f);
        Wh[(size_t)c * 1024 + k0 + kl] = h;
        Wl[(size_t)c * 1024 + k0 + kl] = l;
    }
}

// ---------------------------------------------------------------------------
// z = input @ W_send + b_send via split-f16 MFMA; emits Z_ext [32768][192].
// Block: 256 thr (2x2 waves), 64 rows x 64 cols, BK=64, double-buffered LDS.
// LDS per buf: Ah 8K | Al 8K | Bh 8K | Bl 8K ; XOR swizzle ((row&7)<<4).
__global__ __launch_bounds__(256) void k_send(const float* __restrict__ in,
                                              const _Float16* __restrict__ Wh,
                                              const _Float16* __restrict__ Wl,
                                              const float* __restrict__ bs,
                                              _Float16* __restrict__ Ze) {
    __shared__ char smem[65536];
    const int tid = threadIdx.x;
    const int row0 = blockIdx.x * 64;
    const int wid = tid >> 6, lane = tid & 63;
    const int c15 = lane & 15, g = lane >> 4;
    const int wm = wid >> 1, wn = wid & 1;

    f32x4 accH[2][2], accL[2][2];
    const f32x4 z4 = {0.f, 0.f, 0.f, 0.f};
    #pragma unroll
    for (int mf = 0; mf < 2; ++mf)
        #pragma unroll
        for (int nf = 0; nf < 2; ++nf) { accH[mf][nf] = z4; accL[mf][nf] = z4; }

    int abyte[2], aswz[2], bbyte[2], bswz[2];
    #pragma unroll
    for (int mf = 0; mf < 2; ++mf) {
        int r = wm * 32 + mf * 16 + c15;
        abyte[mf] = r * 128; aswz[mf] = (r & 7) << 4;
    }
    #pragma unroll
    for (int nf = 0; nf < 2; ++nf) {
        int c = wn * 32 + nf * 16 + c15;
        bbyte[nf] = c * 128; bswz[nf] = (c & 7) << 4;
    }
    const int g16 = g * 16;

    // stage B (Wh/Wl k-chunk s) into buffer: gll16, source pre-swizzled
    auto stageB = [&](int buf, int s) {
        char* dst = smem + buf * 32768 + 16384;
        #pragma unroll
        for (int r = 0; r < 2; ++r) {
            int p = r * 4096 + wid * 1024 + lane * 16;
            int row = p >> 7, off = p & 127;
            int soff = off ^ ((row & 7) << 4);
            gll16((const char*)Wh + (size_t)row * 2048 + s * 128 + soff,
                  dst + r * 4096 + wid * 1024);
        }
        #pragma unroll
        for (int r = 0; r < 2; ++r) {
            int p = r * 4096 + wid * 1024 + lane * 16;
            int row = p >> 7, off = p & 127;
            int soff = off ^ ((row & 7) << 4);
            gll16((const char*)Wl + (size_t)row * 2048 + s * 128 + soff,
                  dst + 8192 + r * 4096 + wid * 1024);
        }
    };

    // load A fp32 tile (step s) into regs
    auto loadA = [&](int s, float4* a) {
        #pragma unroll
        for (int it = 0; it < 4; ++it) {
            int q = it * 256 + tid;
            int r = q >> 4, c4 = q & 15;
            a[it] = *(const float4*)&in[(size_t)(row0 + r) * DIN + s * 64 + c4 * 4];
        }
    };

    // convert regs -> split f16, write to buffer (swizzled b64 stores)
    auto writeA = [&](int buf, const float4* a) {
        char* Ah = smem + buf * 32768;
        char* Al = Ah + 8192;
        #pragma unroll
        for (int it = 0; it < 4; ++it) {
            int q = it * 256 + tid;
            int r = q >> 4, c4 = q & 15;
            float v[4] = {a[it].x, a[it].y, a[it].z, a[it].w};
            f16x4 h, l;
            #pragma unroll
            for (int j = 0; j < 4; ++j) {
                _Float16 hh = (_Float16)v[j];
                h[j] = hh;
                l[j] = (_Float16)((v[j] - (float)hh) * 1024.0f);
            }
            int o = r * 128 + ((c4 * 8) ^ ((r & 7) << 4));
            *(f16x4*)(Ah + o) = h;
            *(f16x4*)(Al + o) = l;
        }
    };

    auto compute = [&](int buf) {
        const char* Ah = smem + buf * 32768;
        const char* Al = Ah + 8192;
        const char* Bh = Ah + 16384;
        const char* Bl = Ah + 24576;
        #pragma unroll
        for (int ks = 0; ks < 2; ++ks) {
            int koff = ks * 64 + g16;
            f16x8 bh[2], bl[2];
            #pragma unroll
            for (int nf = 0; nf < 2; ++nf) {
                bh[nf] = *(const f16x8*)(Bh + bbyte[nf] + (koff ^ bswz[nf]));
                bl[nf] = *(const f16x8*)(Bl + bbyte[nf] + (koff ^ bswz[nf]));
            }
            #pragma unroll
            for (int mf = 0; mf < 2; ++mf) {
                f16x8 ah = *(const f16x8*)(Ah + abyte[mf] + (koff ^ aswz[mf]));
                f16x8 al = *(const f16x8*)(Al + abyte[mf] + (koff ^ aswz[mf]));
                #pragma unroll
                for (int nf = 0; nf < 2; ++nf) {
                    accH[mf][nf] = __builtin_amdgcn_mfma_f32_16x16x32_f16(
                        ah, bh[nf], accH[mf][nf], 0, 0, 0);
                    accL[mf][nf] = __builtin_amdgcn_mfma_f32_16x16x32_f16(
                        ah, bl[nf], accL[mf][nf], 0, 0, 0);
                    accL[mf][nf] = __builtin_amdgcn_mfma_f32_16x16x32_f16(
                        al, bh[nf], accL[mf][nf], 0, 0, 0);
                }
            }
        }
    };

    // prologue: stage step 0 into buf0
    {
        float4 a0[4];
        loadA(0, a0);
        stageB(0, 0);
        writeA(0, a0);
    }
    __syncthreads();

    for (int s = 0; s < 16; ++s) {
        int c = s & 1;
        float4 an[4];
        if (s < 15) {
            loadA(s + 1, an);       // issue global loads early
            stageB(c ^ 1, s + 1);   // issue gll early
        }
        compute(c);
        if (s < 15) writeA(c ^ 1, an);
        __syncthreads();
    }

    // epilogue: z = accH + accL/1024 + bias -> split f16 -> Ze
    #pragma unroll
    for (int nf = 0; nf < 2; ++nf) {
        int col = wn * 32 + nf * 16 + c15;
        float bias = bs[col];
        #pragma unroll
        for (int mf = 0; mf < 2; ++mf) {
            #pragma unroll
            for (int r2 = 0; r2 < 4; ++r2) {
                float zv = accH[mf][nf][r2] + accL[mf][nf][r2] * 0.0009765625f + bias;
                _Float16 zh = (_Float16)zv;
                _Float16 z2 = (_Float16)((zv - (float)zh) * 1024.0f);
                int row = row0 + wm * 32 + mf * 16 + g * 4 + r2;
                _Float16* zr = Ze + (size_t)row * 192;
                zr[col]       = z2;
                zr[64 + col]  = zh;
                zr[128 + col] = zh;
            }
        }
    }
}

// ---------------------------------------------------------------------------
// MFMA score kernel: A = E codes (M), B = Z rows (N), K = 192 in 3 chunks.
__global__ __launch_bounds__(512, 2) void k_score(const _Float16* __restrict__ Ee,
                                                  const _Float16* __restrict__ Ze,
                                                  const float* __restrict__ sqr,
                                                  float* __restrict__ pv,
                                                  int* __restrict__ pi) {
    __shared__ char smem[131072];
    const int tid = threadIdx.x;
    const int bx = blockIdx.x;
    const int cb = bx & 15;          // code-chunk of 256
    const int rb = bx >> 4;          // row-block of 256
    const int wid = tid >> 6, lane = tid & 63;
    const int c15 = lane & 15, g = lane >> 4;
    const int wm = wid >> 2, wn = wid & 3;

    const char* EeB = (const char*)(Ee + (size_t)cb * 256 * 192);
    const char* ZeB = (const char*)(Ze + (size_t)rb * 256 * 192);

    f32x4 acc[8][4];
    const f32x4 zz4 = {0.f, 0.f, 0.f, 0.f};
    #pragma unroll
    for (int mf = 0; mf < 8; ++mf)
        #pragma unroll
        for (int nf = 0; nf < 4; ++nf) acc[mf][nf] = zz4;

    int abase[8], aswz[8];
    #pragma unroll
    for (int mf = 0; mf < 8; ++mf) {
        int row = wm*128 + mf*16 + c15;
        abase[mf] = row * 128;
        aswz[mf] = (row & 7) << 4;
    }
    int bbase[4], bswz[4];
    #pragma unroll
    for (int nf = 0; nf < 4; ++nf) {
        int row = wn*64 + nf*16 + c15;
        bbase[nf] = row * 128;
        bswz[nf] = (row & 7) << 4;
    }
    const int g16 = g * 16;

    auto stage = [&](int kc, int b) {
        char* lbase = smem + b * 65536;
        #pragma unroll
        for (int r = 0; r < 4; ++r) {              // A: 256 code rows, 32 KB
            int p = r * 8192 + wid * 1024 + lane * 16;
            int row = p >> 7, off = p & 127;
            int soff = off ^ ((row & 7) << 4);
            gll16(EeB + (size_t)row * 384 + kc * 128 + soff,
                  lbase + r * 8192 + wid * 1024);
        }
        #pragma unroll
        for (int r = 0; r < 4; ++r) {              // B: 256 z rows, 32 KB
            int p = r * 8192 + wid * 1024 + lane * 16;
            int row = p >> 7, off = p & 127;
            int soff = off ^ ((row & 7) << 4);
            gll16(ZeB + (size_t)row * 384 + kc * 128 + soff,
                  lbase + 32768 + r * 8192 + wid * 1024);
        }
    };

    auto compute = [&](int b) {   // b = BUFFER index (0 or 1)
        const char* BA = smem + b * 65536;
        const char* BB = BA + 32768;
        #pragma unroll
        for (int s = 0; s < 2; ++s) {
            const int koff = s * 64 + g16;
            f16x8 bf[4];
            #pragma unroll
            for (int nf = 0; nf < 4; ++nf)
                bf[nf] = *(const f16x8*)(BB + bbase[nf] + (koff ^ bswz[nf]));
            #pragma unroll
            for (int mf = 0; mf < 8; ++mf) {
                f16x8 af = *(const f16x8*)(BA + abase[mf] + (koff ^ aswz[mf]));
                #pragma unroll
                for (int nf = 0; nf < 4; ++nf)
                    acc[mf][nf] = __builtin_amdgcn_mfma_f32_16x16x32_f16(
                        af, bf[nf], acc[mf][nf], 0, 0, 0);
            }
        }
    };

    stage(0, 0);
    __syncthreads();               // buf0 (chunk0) ready
    stage(1, 1);
    compute(0);                    // chunk0: z2*eh   (buf0)
    __syncthreads();               // buf1 (chunk1) ready; buf0 free
    stage(2, 0);
    compute(1);                    // chunk1: + zh*e2 (buf1)
    #pragma unroll
    for (int mf = 0; mf < 8; ++mf) // fold: *= 2^-10
        #pragma unroll
        for (int nf = 0; nf < 4; ++nf)
            acc[mf][nf] *= 0.0009765625f;
    __syncthreads();               // buf0 (chunk2) ready
    compute(0);                    // chunk2: + zh*eh (buf0)
    __syncthreads();

    // ---- epilogue: score + argmin ----
    f32x4 sqv[8];
    const float* sq = sqr + cb * 256 + wm * 128 + g * 4;
    #pragma unroll
    for (int mf = 0; mf < 8; ++mf)
        sqv[mf] = *(const f32x4*)(sq + mf * 16);

    float* redv = (float*)smem;
    int* redi = (int*)(smem + 2048);

    #pragma unroll
    for (int nf = 0; nf < 4; ++nf) {
        float bv = 3.402823466e38f;
        int bi = 0;
        #pragma unroll
        for (int mf = 0; mf < 8; ++mf)
            #pragma unroll
            for (int r2 = 0; r2 < 4; ++r2) {
                float v = sqv[mf][r2] - 2.0f * acc[mf][nf][r2];
                if (v < bv) { bv = v; bi = cb*256 + wm*128 + mf*16 + g*4 + r2; }
            }
        #pragma unroll
        for (int m = 16; m <= 32; m <<= 1) {
            float ov = __shfl_xor(bv, m);
            int oi = __shfl_xor(bi, m);
            if (ov < bv || (ov == bv && oi < bi)) { bv = ov; bi = oi; }
        }
        if (g == 0) {
            int rl = wn * 64 + nf * 16 + c15;
            redv[wm * 256 + rl] = bv;
            redi[wm * 256 + rl] = bi;
        }
    }
    __syncthreads();
    if (tid < 256) {
        float v0 = redv[tid]; int i0 = redi[tid];
        float v1 = redv[256 + tid]; int i1 = redi[256 + tid];
        if (v1 < v0 || (v1 == v0 && i1 < i0)) { v0 = v1; i0 = i1; }
        size_t o = (size_t)cb * 32768 + (size_t)rb * 256 + tid;
        pv[o] = v0;
        pi[o] = i0;
    }
}

// ---------------------------------------------------------------------------
__global__ __launch_bounds__(256) void k_idxfinal(const float* __restrict__ pv,
                                                  const int* __restrict__ pi,
                                                  int* __restrict__ idx,
                                                  float* __restrict__ out_idx,
                                                  int* __restrict__ counts) {
    int r = blockIdx.x * 256 + threadIdx.x;
    float bv = pv[r]; int bi = pi[r];
    #pragma unroll
    for (int c = 1; c < 16; ++c) {
        float v = pv[(size_t)c * 32768 + r];
        int i2 = pi[(size_t)c * 32768 + r];
        if (v < bv || (v == bv && i2 < bi)) { bv = v; bi = i2; }
    }
    idx[r] = bi;
    out_idx[r] = (float)bi;
    atomicAdd(&counts[bi], 1);
}

// ---------------------------------------------------------------------------
__global__ __launch_bounds__(256) void k_loss(const _Float16* __restrict__ Ze,
                                              const float* __restrict__ emb,
                                              const int* __restrict__ idx,
                                              float* __restrict__ partials) {
    int gw = (blockIdx.x * 256 + threadIdx.x) >> 6;
    int lane = threadIdx.x & 63;
    float acc = 0.f;
    for (int r = gw * 32; r < gw * 32 + 32; ++r) {
        int code = idx[r];
        const _Float16* zr = Ze + (size_t)r * 192;
        float z = (float)zr[64 + lane] + (float)zr[lane] * 0.0009765625f;
        float d = z - emb[(size_t)code * DC + lane];
        acc += d * d;
    }
    #pragma unroll
    for (int off = 32; off > 0; off >>= 1) acc += __shfl_down(acc, off);
    if (lane == 0) partials[gw] = acc;
}

// ---------------------------------------------------------------------------
__global__ __launch_bounds__(256) void k_dec(const float* __restrict__ emb,
                                             const float* __restrict__ Wr,
                                             const float* __restrict__ br,
                                             float* __restrict__ D) {
    __shared__ float Ek[64][68];    // [dim][code]
    __shared__ float Wt[64][132];   // [dim][col]
    int cb0  = (blockIdx.x & 63) * 64;
    int col0 = (blockIdx.x >> 6) * 128;
    int tid = threadIdx.x;
    int tx = tid & 15;
    int ty = tid >> 4;

    for (int q = tid; q < 1024; q += 256) {
        int r = q >> 4, c4 = q & 15;
        float4 v = *(const float4*)&emb[(size_t)(cb0 + r) * DC + c4*4];
        Ek[c4*4+0][r] = v.x; Ek[c4*4+1][r] = v.y;
        Ek[c4*4+2][r] = v.z; Ek[c4*4+3][r] = v.w;
    }
    for (int q = tid; q < 2048; q += 256) {
        int c = q >> 5, k4 = q & 31;
        *(float4*)&Wt[c][k4*4] = *(const float4*)&Wr[(size_t)c * DIN + col0 + k4*4];
    }
    __syncthreads();

    float acc[4][8] = {};
    #pragma unroll 8
    for (int c = 0; c < 64; ++c) {
        float4 av = *(const float4*)&Ek[c][tx*4];
        float4 w0 = *(const float4*)&Wt[c][ty*8];
        float4 w1 = *(const float4*)&Wt[c][ty*8 + 4];
        float a[4] = {av.x, av.y, av.z, av.w};
        float w[8] = {w0.x, w0.y, w0.z, w0.w, w1.x, w1.y, w1.z, w1.w};
        #pragma unroll
        for (int i = 0; i < 4; ++i)
            #pragma unroll
            for (int j = 0; j < 8; ++j)
                acc[i][j] += a[i] * w[j];
    }

    #pragma unroll
    for (int i = 0; i < 4; ++i) {
        int code = cb0 + tx*4 + i;
        float4 o0, o1;
        o0.x = acc[i][0] + br[col0 + ty*8 + 0];
        o0.y = acc[i][1] + br[col0 + ty*8 + 1];
        o0.z = acc[i][2] + br[col0 + ty*8 + 2];
        o0.w = acc[i][3] + br[col0 + ty*8 + 3];
        o1.x = acc[i][4] + br[col0 + ty*8 + 4];
        o1.y = acc[i][5] + br[col0 + ty*8 + 5];
        o1.z = acc[i][6] + br[col0 + ty*8 + 6];
        o1.w = acc[i][7] + br[col0 + ty*8 + 7];
        *(float4*)&D[(size_t)code * DIN + col0 + ty*8]     = o0;
        *(float4*)&D[(size_t)code * DIN + col0 + ty*8 + 4] = o1;
    }
}

// ---------------------------------------------------------------------------
__global__ __launch_bounds__(256) void k_gather(const float* __restrict__ D,
                                                const int* __restrict__ idx,
                                                float* __restrict__ x) {
    int gidx = blockIdx.x * 256 + threadIdx.x;
    #pragma unroll
    for (int it = 0; it < 4; ++it) {
        int f = gidx + it * 524288;
        int row = f >> 6, c = f & 63;
        int code = idx[row];
        *(float4*)&x[(size_t)row * DIN + c*4] =
            *(const float4*)&D[(size_t)code * DIN + c*4];
    }
}

// ---------------------------------------------------------------------------
__global__ __launch_bounds__(256) void k_final(const int* __restrict__ counts,
                                               const float* __restrict__ partials,
                                               float* __restrict__ out_sc) {
    __shared__ float red[256];
    int tid = threadIdx.x;

    float lp = 0.f;
    for (int q = tid; q < 1024; q += 256) lp += partials[q];
    red[tid] = lp; __syncthreads();
    for (int s = 128; s > 0; s >>= 1) {
        if (tid < s) red[tid] += red[tid + s];
        __syncthreads();
    }
    float loss = red[0];
    __syncthreads();

    float ep = 0.f;
    for (int k = tid; k < KC; k += 256) {
        int c = counts[k];
        if (c > 0) {
            float p = (float)c / 32768.0f;
            ep += p * logf(p);
        }
    }
    red[tid] = ep; __syncthreads();
    for (int s = 128; s > 0; s >>= 1) {
        if (tid < s) red[tid] += red[tid + s];
        __syncthreads();
    }
    if (tid == 0) {
        out_sc[0] = loss;
        out_sc[1] = loss;
        out_sc[2] = -red[0] * 1.4426950408889634f;
    }
}

// ---------------------------------------------------------------------------
extern "C" void kernel_launch(void* const* d_in, const int* in_sizes, int n_in,
                              void* d_out, int out_size, void* d_ws, size_t ws_size,
                              hipStream_t stream) {
    (void)in_sizes; (void)n_in; (void)out_size; (void)ws_size;
    const float* input  = (const float*)d_in[0];
    const float* W_send = (const float*)d_in[1];
    const float* b_send = (const float*)d_in[2];
    const float* emb    = (const float*)d_in[3];
    const float* W_recv = (const float*)d_in[4];
    const float* b_recv = (const float*)d_in[5];
    float* out = (float*)d_out;

    char* ws = (char*)d_ws;
    _Float16* Ze  = (_Float16*)(ws);                  // 12.6 MB  [32768][192]
    float*    D   = (float*)(ws);                     // 16.8 MB — aliases Ze (Ze dead before k_dec)
    float*    pvb = (float*)(ws + 16777216);          //  2 MB
    int*      pib = (int*)  (ws + 18874368);          //  2 MB
    _Float16* Ee  = (_Float16*)(ws + 20971520);       //  1.5 MB [4096][192]
    float*    sqr = (float*)(ws + 22544384);          // 16 KB
    int*      idx = (int*)  (ws + 22560768);          // 128 KB
    int*   counts = (int*)  (ws + 22691840);          // 16 KB
    float* lpart  = (float*)(ws + 22708224);          //  4 KB
    _Float16* Wh  = (_Float16*)(ws + 22712320);       // 128 KB [64][1024]
    _Float16* Wl  = (_Float16*)(ws + 22843392);       // 128 KB [64][1024]

    float* out_x   = out;                    // 33554432
    float* out_idx = out + 33554432;         // 32768
    float* out_sc  = out + 33587200;         // 3

    hipMemsetAsync(counts, 0, KC * sizeof(int), stream);

    k_prep<<<1024, 256, 0, stream>>>(emb, Ee, sqr);
    k_prepw<<<16, 256, 0, stream>>>(W_send, Wh, Wl);
    k_send<<<512, 256, 0, stream>>>(input, Wh, Wl, b_send, Ze);
    k_score<<<2048, 512, 0, stream>>>(Ee, Ze, sqr, pvb, pib);
    k_idxfinal<<<128, 256, 0, stream>>>(pvb, pib, idx, out_idx, counts);
    k_loss<<<256, 256, 0, stream>>>(Ze, emb, idx, lpart);   // before k_dec (Ze alias)
    k_dec<<<512, 256, 0, stream>>>(emb, W_recv, b_recv, D);
    k_gather<<<2048, 256, 0, stream>>>(D, idx, out_x);
    k_final<<<1, 256, 0, stream>>>(counts, lpart, out_sc);
}

// Round 6
// 135.728 us; speedup vs baseline: 2.8972x; 1.1569x over previous
//
#include <hip/hip_runtime.h>

#define DIN 1024
#define DC 64
#define KC 4096

typedef _Float16 f16x8 __attribute__((ext_vector_type(8)));
typedef _Float16 f16x4 __attribute__((ext_vector_type(4)));
typedef float f32x4 __attribute__((ext_vector_type(4)));

__device__ __forceinline__ void gll16(const void* g, void* l) {
    __builtin_amdgcn_global_load_lds(
        (const __attribute__((address_space(1))) unsigned int*)g,
        (__attribute__((address_space(3))) unsigned int*)l, 16, 0, 0);
}

// ---------------------------------------------------------------------------
// Ee [4096][128] f16 = [eh | e2], e2 = (e - eh)*1024 ; sqr[k] fp32.
__global__ __launch_bounds__(256) void k_prep(const float* __restrict__ emb,
                                              _Float16* __restrict__ Ee,
                                              float* __restrict__ sqr) {
    int code = blockIdx.x * 4 + (threadIdx.x >> 6);
    int lane = threadIdx.x & 63;
    float v = emb[(size_t)code * DC + lane];
    _Float16 eh = (_Float16)v;
    _Float16 e2 = (_Float16)((v - (float)eh) * 1024.0f);
    _Float16* row = Ee + (size_t)code * 128;
    row[lane]      = eh;   // slot0: pairs with z2 (and zh in the eh*zh pass)
    row[64 + lane] = e2;   // slot1: pairs with zh
    float s = v * v;
    #pragma unroll
    for (int m = 1; m < 64; m <<= 1) s += __shfl_xor(s, m);
    if (lane == 0) sqr[code] = s;
}

// ---------------------------------------------------------------------------
// W_send [1024][64] fp32 -> Wh/Wl [64][1024] f16 (transposed, split)
__global__ __launch_bounds__(256) void k_prepw(const float* __restrict__ Ws,
                                               _Float16* __restrict__ Wh,
                                               _Float16* __restrict__ Wl) {
    int k0 = blockIdx.x * 64;   // 16 blocks
    int tid = threadIdx.x;
    #pragma unroll
    for (int it = 0; it < 16; ++it) {
        int q = it * 256 + tid;          // 4096 = 64c x 64k
        int c = q >> 6, kl = q & 63;
        float v = Ws[(size_t)(k0 + kl) * 64 + c];
        _Float16 h = (_Float16)v;
        _Float16 l = (_Float16)((v - (float)h) * 1024.0f);
        Wh[(size_t)c * 1024 + k0 + kl] = h;
        Wl[(size_t)c * 1024 + k0 + kl] = l;
    }
}

// ---------------------------------------------------------------------------
// z = input @ W_send + b_send via split-f16 MFMA; emits Ze [32768][128] = [z2|zh].
__global__ __launch_bounds__(256) void k_send(const float* __restrict__ in,
                                              const _Float16* __restrict__ Wh,
                                              const _Float16* __restrict__ Wl,
                                              const float* __restrict__ bs,
                                              _Float16* __restrict__ Ze) {
    __shared__ char smem[65536];
    const int tid = threadIdx.x;
    const int row0 = blockIdx.x * 64;
    const int wid = tid >> 6, lane = tid & 63;
    const int c15 = lane & 15, g = lane >> 4;
    const int wm = wid >> 1, wn = wid & 1;

    f32x4 accH[2][2], accL[2][2];
    const f32x4 z4 = {0.f, 0.f, 0.f, 0.f};
    #pragma unroll
    for (int mf = 0; mf < 2; ++mf)
        #pragma unroll
        for (int nf = 0; nf < 2; ++nf) { accH[mf][nf] = z4; accL[mf][nf] = z4; }

    int abyte[2], aswz[2], bbyte[2], bswz[2];
    #pragma unroll
    for (int mf = 0; mf < 2; ++mf) {
        int r = wm * 32 + mf * 16 + c15;
        abyte[mf] = r * 128; aswz[mf] = (r & 7) << 4;
    }
    #pragma unroll
    for (int nf = 0; nf < 2; ++nf) {
        int c = wn * 32 + nf * 16 + c15;
        bbyte[nf] = c * 128; bswz[nf] = (c & 7) << 4;
    }
    const int g16 = g * 16;

    auto stageB = [&](int buf, int s) {
        char* dst = smem + buf * 32768 + 16384;
        #pragma unroll
        for (int r = 0; r < 2; ++r) {
            int p = r * 4096 + wid * 1024 + lane * 16;
            int row = p >> 7, off = p & 127;
            int soff = off ^ ((row & 7) << 4);
            gll16((const char*)Wh + (size_t)row * 2048 + s * 128 + soff,
                  dst + r * 4096 + wid * 1024);
        }
        #pragma unroll
        for (int r = 0; r < 2; ++r) {
            int p = r * 4096 + wid * 1024 + lane * 16;
            int row = p >> 7, off = p & 127;
            int soff = off ^ ((row & 7) << 4);
            gll16((const char*)Wl + (size_t)row * 2048 + s * 128 + soff,
                  dst + 8192 + r * 4096 + wid * 1024);
        }
    };

    auto loadA = [&](int s, float4* a) {
        #pragma unroll
        for (int it = 0; it < 4; ++it) {
            int q = it * 256 + tid;
            int r = q >> 4, c4 = q & 15;
            a[it] = *(const float4*)&in[(size_t)(row0 + r) * DIN + s * 64 + c4 * 4];
        }
    };

    auto writeA = [&](int buf, const float4* a) {
        char* Ah = smem + buf * 32768;
        char* Al = Ah + 8192;
        #pragma unroll
        for (int it = 0; it < 4; ++it) {
            int q = it * 256 + tid;
            int r = q >> 4, c4 = q & 15;
            float v[4] = {a[it].x, a[it].y, a[it].z, a[it].w};
            f16x4 h, l;
            #pragma unroll
            for (int j = 0; j < 4; ++j) {
                _Float16 hh = (_Float16)v[j];
                h[j] = hh;
                l[j] = (_Float16)((v[j] - (float)hh) * 1024.0f);
            }
            int o = r * 128 + ((c4 * 8) ^ ((r & 7) << 4));
            *(f16x4*)(Ah + o) = h;
            *(f16x4*)(Al + o) = l;
        }
    };

    auto compute = [&](int buf) {
        const char* Ah = smem + buf * 32768;
        const char* Al = Ah + 8192;
        const char* Bh = Ah + 16384;
        const char* Bl = Ah + 24576;
        #pragma unroll
        for (int ks = 0; ks < 2; ++ks) {
            int koff = ks * 64 + g16;
            f16x8 bh[2], bl[2];
            #pragma unroll
            for (int nf = 0; nf < 2; ++nf) {
                bh[nf] = *(const f16x8*)(Bh + bbyte[nf] + (koff ^ bswz[nf]));
                bl[nf] = *(const f16x8*)(Bl + bbyte[nf] + (koff ^ bswz[nf]));
            }
            #pragma unroll
            for (int mf = 0; mf < 2; ++mf) {
                f16x8 ah = *(const f16x8*)(Ah + abyte[mf] + (koff ^ aswz[mf]));
                f16x8 al = *(const f16x8*)(Al + abyte[mf] + (koff ^ aswz[mf]));
                #pragma unroll
                for (int nf = 0; nf < 2; ++nf) {
                    accH[mf][nf] = __builtin_amdgcn_mfma_f32_16x16x32_f16(
                        ah, bh[nf], accH[mf][nf], 0, 0, 0);
                    accL[mf][nf] = __builtin_amdgcn_mfma_f32_16x16x32_f16(
                        ah, bl[nf], accL[mf][nf], 0, 0, 0);
                    accL[mf][nf] = __builtin_amdgcn_mfma_f32_16x16x32_f16(
                        al, bh[nf], accL[mf][nf], 0, 0, 0);
                }
            }
        }
    };

    {
        float4 a0[4];
        loadA(0, a0);
        stageB(0, 0);
        writeA(0, a0);
    }
    __syncthreads();

    for (int s = 0; s < 16; ++s) {
        int c = s & 1;
        float4 an[4];
        if (s < 15) {
            loadA(s + 1, an);
            stageB(c ^ 1, s + 1);
        }
        compute(c);
        if (s < 15) writeA(c ^ 1, an);
        __syncthreads();
    }

    // epilogue: z = accH + accL/1024 + bias -> [z2|zh] f16 -> Ze
    #pragma unroll
    for (int nf = 0; nf < 2; ++nf) {
        int col = wn * 32 + nf * 16 + c15;
        float bias = bs[col];
        #pragma unroll
        for (int mf = 0; mf < 2; ++mf) {
            #pragma unroll
            for (int r2 = 0; r2 < 4; ++r2) {
                float zv = accH[mf][nf][r2] + accL[mf][nf][r2] * 0.0009765625f + bias;
                _Float16 zh = (_Float16)zv;
                _Float16 z2 = (_Float16)((zv - (float)zh) * 1024.0f);
                int row = row0 + wm * 32 + mf * 16 + g * 4 + r2;
                _Float16* zr = Ze + (size_t)row * 128;
                zr[col]      = z2;
                zr[64 + col] = zh;
            }
        }
    }
}

// ---------------------------------------------------------------------------
// Persistent-Z score kernel. Grid 256 x 512 thr; block = 128 rows, loops all
// 4096 codes in 32 chunks of 128. Z-frags in registers; E-tile double-buffered
// in LDS (32 KB/chunk, [eh|e2]); per-chunk in-register argmin; writes final
// idx/out_idx/counts directly.
__global__ __launch_bounds__(512, 2) void k_score(const _Float16* __restrict__ Ee,
                                                  const _Float16* __restrict__ Ze,
                                                  const float* __restrict__ sqr,
                                                  int* __restrict__ idx,
                                                  float* __restrict__ out_idx,
                                                  int* __restrict__ counts) {
    __shared__ char smem[69632];          // 2x32KB E dbuf + 4KB reduce
    const int tid = threadIdx.x;
    const int row0 = blockIdx.x * 128;
    const int wid = tid >> 6, lane = tid & 63;
    const int c15 = lane & 15, g = lane >> 4;
    const int wm = wid >> 1;              // 0..3 : codes wm*32..+31
    const int wn = wid & 1;               // 0..1 : rows  wn*64..+63
    const int g16 = g * 16;

    // ---- Z fragments: load once from global into registers ----
    f16x8 zf2[2][4], zfh[2][4];           // [kstep j][nf]
    #pragma unroll
    for (int nf = 0; nf < 4; ++nf) {
        const _Float16* zr = Ze + (size_t)(row0 + wn * 64 + nf * 16 + c15) * 128;
        #pragma unroll
        for (int j = 0; j < 2; ++j) {
            zf2[j][nf] = *(const f16x8*)(zr + j * 32 + g * 8);        // z2
            zfh[j][nf] = *(const f16x8*)(zr + 64 + j * 32 + g * 8);   // zh
        }
    }

    // A addressing (code rows in LDS, 256 B/row, XOR-swizzled by (r&15)<<4)
    int rbase[2], rx[2];
    #pragma unroll
    for (int mf = 0; mf < 2; ++mf) {
        int r = wm * 32 + mf * 16 + c15;
        rbase[mf] = r * 256;
        rx[mf] = (r & 15) << 4;
    }

    auto stage = [&](int ch, int buf) {
        char* dst = smem + buf * 32768;
        const char* src = (const char*)Ee + (size_t)ch * 32768;
        #pragma unroll
        for (int t = 0; t < 4; ++t) {
            int p = t * 8192 + tid * 16;
            int r = p >> 8, b = p & 255;
            gll16(src + r * 256 + (b ^ ((r & 15) << 4)), dst + p);
        }
    };

    float bv[4];
    int   bi[4];
    #pragma unroll
    for (int nf = 0; nf < 4; ++nf) { bv[nf] = 3.402823466e38f; bi[nf] = 0; }

    const f32x4 zz4 = {0.f, 0.f, 0.f, 0.f};
    static const int koffs[6] = {0, 64, 128, 192, 0, 64};   // A byte offsets/kstep

    stage(0, 0);
    __syncthreads();

    for (int ch = 0; ch < 32; ++ch) {
        const int buf = ch & 1;
        // prefetch sq for this chunk (L2-resident)
        f32x4 sqv[2];
        #pragma unroll
        for (int mf = 0; mf < 2; ++mf)
            sqv[mf] = *(const f32x4*)(sqr + ch * 128 + wm * 32 + mf * 16 + g * 4);

        if (ch < 31) stage(ch + 1, buf ^ 1);

        const char* base = smem + buf * 32768;
        f32x4 accL[2][4], accH[2][4];
        #pragma unroll
        for (int j = 0; j < 6; ++j) {
            const int kraw = koffs[j] + g16;
            f16x8 af[2];
            #pragma unroll
            for (int mf = 0; mf < 2; ++mf)
                af[mf] = *(const f16x8*)(base + rbase[mf] + (kraw ^ rx[mf]));
            #pragma unroll
            for (int mf = 0; mf < 2; ++mf) {
                #pragma unroll
                for (int nf = 0; nf < 4; ++nf) {
                    if (j == 0)
                        accL[mf][nf] = __builtin_amdgcn_mfma_f32_16x16x32_f16(
                            af[mf], zf2[0][nf], zz4, 0, 0, 0);
                    else if (j == 1)
                        accL[mf][nf] = __builtin_amdgcn_mfma_f32_16x16x32_f16(
                            af[mf], zf2[1][nf], accL[mf][nf], 0, 0, 0);
                    else if (j < 4)
                        accL[mf][nf] = __builtin_amdgcn_mfma_f32_16x16x32_f16(
                            af[mf], zfh[j - 2][nf], accL[mf][nf], 0, 0, 0);
                    else if (j == 4)
                        accH[mf][nf] = __builtin_amdgcn_mfma_f32_16x16x32_f16(
                            af[mf], zfh[0][nf], zz4, 0, 0, 0);
                    else
                        accH[mf][nf] = __builtin_amdgcn_mfma_f32_16x16x32_f16(
                            af[mf], zfh[1][nf], accH[mf][nf], 0, 0, 0);
                }
            }
        }

        // score + running argmin.  score = sq - 2*accH - accL/512
        #pragma unroll
        for (int nf = 0; nf < 4; ++nf) {
            #pragma unroll
            for (int mf = 0; mf < 2; ++mf) {
                f32x4 v = sqv[mf] - accH[mf][nf] * 2.0f
                                  - accL[mf][nf] * 0.001953125f;
                #pragma unroll
                for (int r2 = 0; r2 < 4; ++r2) {
                    if (v[r2] < bv[nf]) {
                        bv[nf] = v[r2];
                        bi[nf] = ch * 128 + wm * 32 + mf * 16 + g * 4 + r2;
                    }
                }
            }
        }
        __syncthreads();   // staging of ch+1 done; buf free for ch+2
    }

    // ---- final reduction ----
    float* redv = (float*)(smem + 65536);         // [4][128]
    int*   redi = (int*)(smem + 65536 + 2048);    // [4][128]
    #pragma unroll
    for (int nf = 0; nf < 4; ++nf) {
        float v_ = bv[nf]; int i_ = bi[nf];
        #pragma unroll
        for (int m = 16; m <= 32; m <<= 1) {
            float ov = __shfl_xor(v_, m);
            int oi = __shfl_xor(i_, m);
            if (ov < v_ || (ov == v_ && oi < i_)) { v_ = ov; i_ = oi; }
        }
        if (g == 0) {
            int rl = wn * 64 + nf * 16 + c15;
            redv[wm * 128 + rl] = v_;
            redi[wm * 128 + rl] = i_;
        }
    }
    __syncthreads();
    if (tid < 128) {
        float v0 = redv[tid]; int i0 = redi[tid];
        #pragma unroll
        for (int w = 1; w < 4; ++w) {
            float v1 = redv[w * 128 + tid]; int i1 = redi[w * 128 + tid];
            if (v1 < v0 || (v1 == v0 && i1 < i0)) { v0 = v1; i0 = i1; }
        }
        int grow = row0 + tid;
        idx[grow] = i0;
        out_idx[grow] = (float)i0;
        atomicAdd(&counts[i0], 1);
    }
}

// ---------------------------------------------------------------------------
// loss partials from Ze (z = zh + z2/1024) and emb.
__global__ __launch_bounds__(256) void k_loss(const _Float16* __restrict__ Ze,
                                              const float* __restrict__ emb,
                                              const int* __restrict__ idx,
                                              float* __restrict__ partials) {
    int gw = (blockIdx.x * 256 + threadIdx.x) >> 6;
    int lane = threadIdx.x & 63;
    float acc = 0.f;
    for (int r = gw * 32; r < gw * 32 + 32; ++r) {
        int code = idx[r];
        const _Float16* zr = Ze + (size_t)r * 128;
        float z = (float)zr[64 + lane] + (float)zr[lane] * 0.0009765625f;
        float d = z - emb[(size_t)code * DC + lane];
        acc += d * d;
    }
    #pragma unroll
    for (int off = 32; off > 0; off >>= 1) acc += __shfl_down(acc, off);
    if (lane == 0) partials[gw] = acc;
}

// ---------------------------------------------------------------------------
__global__ __launch_bounds__(256) void k_dec(const float* __restrict__ emb,
                                             const float* __restrict__ Wr,
                                             const float* __restrict__ br,
                                             float* __restrict__ D) {
    __shared__ float Ek[64][68];    // [dim][code]
    __shared__ float Wt[64][132];   // [dim][col]
    int cb0  = (blockIdx.x & 63) * 64;
    int col0 = (blockIdx.x >> 6) * 128;
    int tid = threadIdx.x;
    int tx = tid & 15;
    int ty = tid >> 4;

    for (int q = tid; q < 1024; q += 256) {
        int r = q >> 4, c4 = q & 15;
        float4 v = *(const float4*)&emb[(size_t)(cb0 + r) * DC + c4*4];
        Ek[c4*4+0][r] = v.x; Ek[c4*4+1][r] = v.y;
        Ek[c4*4+2][r] = v.z; Ek[c4*4+3][r] = v.w;
    }
    for (int q = tid; q < 2048; q += 256) {
        int c = q >> 5, k4 = q & 31;
        *(float4*)&Wt[c][k4*4] = *(const float4*)&Wr[(size_t)c * DIN + col0 + k4*4];
    }
    __syncthreads();

    float acc[4][8] = {};
    #pragma unroll 8
    for (int c = 0; c < 64; ++c) {
        float4 av = *(const float4*)&Ek[c][tx*4];
        float4 w0 = *(const float4*)&Wt[c][ty*8];
        float4 w1 = *(const float4*)&Wt[c][ty*8 + 4];
        float a[4] = {av.x, av.y, av.z, av.w};
        float w[8] = {w0.x, w0.y, w0.z, w0.w, w1.x, w1.y, w1.z, w1.w};
        #pragma unroll
        for (int i = 0; i < 4; ++i)
            #pragma unroll
            for (int j = 0; j < 8; ++j)
                acc[i][j] += a[i] * w[j];
    }

    #pragma unroll
    for (int i = 0; i < 4; ++i) {
        int code = cb0 + tx*4 + i;
        float4 o0, o1;
        o0.x = acc[i][0] + br[col0 + ty*8 + 0];
        o0.y = acc[i][1] + br[col0 + ty*8 + 1];
        o0.z = acc[i][2] + br[col0 + ty*8 + 2];
        o0.w = acc[i][3] + br[col0 + ty*8 + 3];
        o1.x = acc[i][4] + br[col0 + ty*8 + 4];
        o1.y = acc[i][5] + br[col0 + ty*8 + 5];
        o1.z = acc[i][6] + br[col0 + ty*8 + 6];
        o1.w = acc[i][7] + br[col0 + ty*8 + 7];
        *(float4*)&D[(size_t)code * DIN + col0 + ty*8]     = o0;
        *(float4*)&D[(size_t)code * DIN + col0 + ty*8 + 4] = o1;
    }
}

// ---------------------------------------------------------------------------
__global__ __launch_bounds__(256) void k_gather(const float* __restrict__ D,
                                                const int* __restrict__ idx,
                                                float* __restrict__ x) {
    int gidx = blockIdx.x * 256 + threadIdx.x;
    #pragma unroll
    for (int it = 0; it < 4; ++it) {
        int f = gidx + it * 524288;
        int row = f >> 6, c = f & 63;
        int code = idx[row];
        *(float4*)&x[(size_t)row * DIN + c*4] =
            *(const float4*)&D[(size_t)code * DIN + c*4];
    }
}

// ---------------------------------------------------------------------------
__global__ __launch_bounds__(256) void k_final(const int* __restrict__ counts,
                                               const float* __restrict__ partials,
                                               float* __restrict__ out_sc) {
    __shared__ float red[256];
    int tid = threadIdx.x;

    float lp = 0.f;
    for (int q = tid; q < 1024; q += 256) lp += partials[q];
    red[tid] = lp; __syncthreads();
    for (int s = 128; s > 0; s >>= 1) {
        if (tid < s) red[tid] += red[tid + s];
        __syncthreads();
    }
    float loss = red[0];
    __syncthreads();

    float ep = 0.f;
    for (int k = tid; k < KC; k += 256) {
        int c = counts[k];
        if (c > 0) {
            float p = (float)c / 32768.0f;
            ep += p * logf(p);
        }
    }
    red[tid] = ep; __syncthreads();
    for (int s = 128; s > 0; s >>= 1) {
        if (tid < s) red[tid] += red[tid + s];
        __syncthreads();
    }
    if (tid == 0) {
        out_sc[0] = loss;
        out_sc[1] = loss;
        out_sc[2] = -red[0] * 1.4426950408889634f;
    }
}

// ---------------------------------------------------------------------------
extern "C" void kernel_launch(void* const* d_in, const int* in_sizes, int n_in,
                              void* d_out, int out_size, void* d_ws, size_t ws_size,
                              hipStream_t stream) {
    (void)in_sizes; (void)n_in; (void)out_size; (void)ws_size;
    const float* input  = (const float*)d_in[0];
    const float* W_send = (const float*)d_in[1];
    const float* b_send = (const float*)d_in[2];
    const float* emb    = (const float*)d_in[3];
    const float* W_recv = (const float*)d_in[4];
    const float* b_recv = (const float*)d_in[5];
    float* out = (float*)d_out;

    char* ws = (char*)d_ws;
    _Float16* Ze  = (_Float16*)(ws);                  //  8 MB  [32768][128]
    float*    D   = (float*)(ws);                     // 16 MB — aliases Ze (Ze dead before k_dec)
    _Float16* Ee  = (_Float16*)(ws + 16777216);       //  1 MB  [4096][128]
    float*    sqr = (float*)(ws + 17825792);          // 16 KB
    int*      idx = (int*)  (ws + 17842176);          // 128 KB
    int*   counts = (int*)  (ws + 17973248);          // 16 KB
    float* lpart  = (float*)(ws + 17989632);          //  4 KB
    _Float16* Wh  = (_Float16*)(ws + 17993728);       // 128 KB [64][1024]
    _Float16* Wl  = (_Float16*)(ws + 18124800);       // 128 KB [64][1024]

    float* out_x   = out;                    // 33554432
    float* out_idx = out + 33554432;         // 32768
    float* out_sc  = out + 33587200;         // 3

    hipMemsetAsync(counts, 0, KC * sizeof(int), stream);

    k_prep<<<1024, 256, 0, stream>>>(emb, Ee, sqr);
    k_prepw<<<16, 256, 0, stream>>>(W_send, Wh, Wl);
    k_send<<<512, 256, 0, stream>>>(input, Wh, Wl, b_send, Ze);
    k_score<<<256, 512, 0, stream>>>(Ee, Ze, sqr, idx, out_idx, counts);
    k_loss<<<256, 256, 0, stream>>>(Ze, emb, idx, lpart);   // before k_dec (Ze alias)
    k_dec<<<512, 256, 0, stream>>>(emb, W_recv, b_recv, D);
    k_gather<<<2048, 256, 0, stream>>>(D, idx, out_x);
    k_final<<<1, 256, 0, stream>>>(counts, lpart, out_sc);
}

// Round 7
// 125.119 us; speedup vs baseline: 3.1429x; 1.0848x over previous
//
#include <hip/hip_runtime.h>

#define DIN 1024
#define DC 64
#define KC 4096

typedef _Float16 f16x8 __attribute__((ext_vector_type(8)));
typedef _Float16 f16x4 __attribute__((ext_vector_type(4)));
typedef float f32x4 __attribute__((ext_vector_type(4)));

__device__ __forceinline__ void gll16(const void* g, void* l) {
    __builtin_amdgcn_global_load_lds(
        (const __attribute__((address_space(1))) unsigned int*)g,
        (__attribute__((address_space(3))) unsigned int*)l, 16, 0, 0);
}

// ---------------------------------------------------------------------------
// Merged prep. Blocks 0..1023:  Ee [4096][128] f16 = [eh|e2], sqr, zero counts.
//              Blocks 1024..1039: W_send -> Wh/Wl [64][1024] f16 (transposed).
__global__ __launch_bounds__(256) void k_prep(const float* __restrict__ emb,
                                              const float* __restrict__ Ws,
                                              _Float16* __restrict__ Ee,
                                              float* __restrict__ sqr,
                                              _Float16* __restrict__ Wh,
                                              _Float16* __restrict__ Wl,
                                              int* __restrict__ counts) {
    int b = blockIdx.x;
    int tid = threadIdx.x;
    if (b < 1024) {
        int code = b * 4 + (tid >> 6);
        int lane = tid & 63;
        float v = emb[(size_t)code * DC + lane];
        _Float16 eh = (_Float16)v;
        _Float16 e2 = (_Float16)((v - (float)eh) * 1024.0f);
        _Float16* row = Ee + (size_t)code * 128;
        row[lane]      = eh;
        row[64 + lane] = e2;
        float s = v * v;
        #pragma unroll
        for (int m = 1; m < 64; m <<= 1) s += __shfl_xor(s, m);
        if (lane == 0) sqr[code] = s;
        if (tid < 4) counts[b * 4 + tid] = 0;
    } else {
        int k0 = (b - 1024) * 64;
        #pragma unroll
        for (int it = 0; it < 16; ++it) {
            int q = it * 256 + tid;          // 4096 = 64c x 64k
            int c = q >> 6, kl = q & 63;
            float v = Ws[(size_t)(k0 + kl) * 64 + c];
            _Float16 h = (_Float16)v;
            _Float16 l = (_Float16)((v - (float)h) * 1024.0f);
            Wh[(size_t)c * 1024 + k0 + kl] = h;
            Wl[(size_t)c * 1024 + k0 + kl] = l;
        }
    }
}

// ---------------------------------------------------------------------------
// z = input @ W_send + b_send via split-f16 MFMA; emits Ze [32768][128] = [z2|zh].
__global__ __launch_bounds__(256) void k_send(const float* __restrict__ in,
                                              const _Float16* __restrict__ Wh,
                                              const _Float16* __restrict__ Wl,
                                              const float* __restrict__ bs,
                                              _Float16* __restrict__ Ze) {
    __shared__ char smem[65536];
    const int tid = threadIdx.x;
    const int row0 = blockIdx.x * 64;
    const int wid = tid >> 6, lane = tid & 63;
    const int c15 = lane & 15, g = lane >> 4;
    const int wm = wid >> 1, wn = wid & 1;

    f32x4 accH[2][2], accL[2][2];
    const f32x4 z4 = {0.f, 0.f, 0.f, 0.f};
    #pragma unroll
    for (int mf = 0; mf < 2; ++mf)
        #pragma unroll
        for (int nf = 0; nf < 2; ++nf) { accH[mf][nf] = z4; accL[mf][nf] = z4; }

    int abyte[2], aswz[2], bbyte[2], bswz[2];
    #pragma unroll
    for (int mf = 0; mf < 2; ++mf) {
        int r = wm * 32 + mf * 16 + c15;
        abyte[mf] = r * 128; aswz[mf] = (r & 7) << 4;
    }
    #pragma unroll
    for (int nf = 0; nf < 2; ++nf) {
        int c = wn * 32 + nf * 16 + c15;
        bbyte[nf] = c * 128; bswz[nf] = (c & 7) << 4;
    }
    const int g16 = g * 16;

    auto stageB = [&](int buf, int s) {
        char* dst = smem + buf * 32768 + 16384;
        #pragma unroll
        for (int r = 0; r < 2; ++r) {
            int p = r * 4096 + wid * 1024 + lane * 16;
            int row = p >> 7, off = p & 127;
            int soff = off ^ ((row & 7) << 4);
            gll16((const char*)Wh + (size_t)row * 2048 + s * 128 + soff,
                  dst + r * 4096 + wid * 1024);
        }
        #pragma unroll
        for (int r = 0; r < 2; ++r) {
            int p = r * 4096 + wid * 1024 + lane * 16;
            int row = p >> 7, off = p & 127;
            int soff = off ^ ((row & 7) << 4);
            gll16((const char*)Wl + (size_t)row * 2048 + s * 128 + soff,
                  dst + 8192 + r * 4096 + wid * 1024);
        }
    };

    auto loadA = [&](int s, float4* a) {
        #pragma unroll
        for (int it = 0; it < 4; ++it) {
            int q = it * 256 + tid;
            int r = q >> 4, c4 = q & 15;
            a[it] = *(const float4*)&in[(size_t)(row0 + r) * DIN + s * 64 + c4 * 4];
        }
    };

    auto writeA = [&](int buf, const float4* a) {
        char* Ah = smem + buf * 32768;
        char* Al = Ah + 8192;
        #pragma unroll
        for (int it = 0; it < 4; ++it) {
            int q = it * 256 + tid;
            int r = q >> 4, c4 = q & 15;
            float v[4] = {a[it].x, a[it].y, a[it].z, a[it].w};
            f16x4 h, l;
            #pragma unroll
            for (int j = 0; j < 4; ++j) {
                _Float16 hh = (_Float16)v[j];
                h[j] = hh;
                l[j] = (_Float16)((v[j] - (float)hh) * 1024.0f);
            }
            int o = r * 128 + ((c4 * 8) ^ ((r & 7) << 4));
            *(f16x4*)(Ah + o) = h;
            *(f16x4*)(Al + o) = l;
        }
    };

    auto compute = [&](int buf) {
        const char* Ah = smem + buf * 32768;
        const char* Al = Ah + 8192;
        const char* Bh = Ah + 16384;
        const char* Bl = Ah + 24576;
        #pragma unroll
        for (int ks = 0; ks < 2; ++ks) {
            int koff = ks * 64 + g16;
            f16x8 bh[2], bl[2];
            #pragma unroll
            for (int nf = 0; nf < 2; ++nf) {
                bh[nf] = *(const f16x8*)(Bh + bbyte[nf] + (koff ^ bswz[nf]));
                bl[nf] = *(const f16x8*)(Bl + bbyte[nf] + (koff ^ bswz[nf]));
            }
            #pragma unroll
            for (int mf = 0; mf < 2; ++mf) {
                f16x8 ah = *(const f16x8*)(Ah + abyte[mf] + (koff ^ aswz[mf]));
                f16x8 al = *(const f16x8*)(Al + abyte[mf] + (koff ^ aswz[mf]));
                #pragma unroll
                for (int nf = 0; nf < 2; ++nf) {
                    accH[mf][nf] = __builtin_amdgcn_mfma_f32_16x16x32_f16(
                        ah, bh[nf], accH[mf][nf], 0, 0, 0);
                    accL[mf][nf] = __builtin_amdgcn_mfma_f32_16x16x32_f16(
                        ah, bl[nf], accL[mf][nf], 0, 0, 0);
                    accL[mf][nf] = __builtin_amdgcn_mfma_f32_16x16x32_f16(
                        al, bh[nf], accL[mf][nf], 0, 0, 0);
                }
            }
        }
    };

    {
        float4 a0[4];
        loadA(0, a0);
        stageB(0, 0);
        writeA(0, a0);
    }
    __syncthreads();

    for (int s = 0; s < 16; ++s) {
        int c = s & 1;
        float4 an[4];
        if (s < 15) {
            loadA(s + 1, an);
            stageB(c ^ 1, s + 1);
        }
        compute(c);
        if (s < 15) writeA(c ^ 1, an);
        __syncthreads();
    }

    // epilogue: z = accH + accL/1024 + bias -> [z2|zh] f16 -> Ze
    #pragma unroll
    for (int nf = 0; nf < 2; ++nf) {
        int col = wn * 32 + nf * 16 + c15;
        float bias = bs[col];
        #pragma unroll
        for (int mf = 0; mf < 2; ++mf) {
            #pragma unroll
            for (int r2 = 0; r2 < 4; ++r2) {
                float zv = accH[mf][nf][r2] + accL[mf][nf][r2] * 0.0009765625f + bias;
                _Float16 zh = (_Float16)zv;
                _Float16 z2 = (_Float16)((zv - (float)zh) * 1024.0f);
                int row = row0 + wm * 32 + mf * 16 + g * 4 + r2;
                _Float16* zr = Ze + (size_t)row * 128;
                zr[col]      = z2;
                zr[64 + col] = zh;
            }
        }
    }
}

// ---------------------------------------------------------------------------
// Persistent-Z score kernel + fused loss.
// Per-row loss = best_score + ||z||^2  (best_score = sqr - 2<z,e>), so the
// loss comes free from the argmin; per-block partial -> lpart[block].
__global__ __launch_bounds__(512, 2) void k_score(const _Float16* __restrict__ Ee,
                                                  const _Float16* __restrict__ Ze,
                                                  const float* __restrict__ sqr,
                                                  int* __restrict__ idx,
                                                  float* __restrict__ out_idx,
                                                  int* __restrict__ counts,
                                                  float* __restrict__ lpart) {
    __shared__ char smem[70656];          // 2x32KB E dbuf + 4.5KB reduce
    const int tid = threadIdx.x;
    const int row0 = blockIdx.x * 128;
    const int wid = tid >> 6, lane = tid & 63;
    const int c15 = lane & 15, g = lane >> 4;
    const int wm = wid >> 1;              // 0..3 : codes wm*32..+31
    const int wn = wid & 1;               // 0..1 : rows  wn*64..+63
    const int g16 = g * 16;

    // ---- Z fragments: load once from global into registers ----
    f16x8 zf2[2][4], zfh[2][4];           // [kstep j][nf]
    #pragma unroll
    for (int nf = 0; nf < 4; ++nf) {
        const _Float16* zr = Ze + (size_t)(row0 + wn * 64 + nf * 16 + c15) * 128;
        #pragma unroll
        for (int j = 0; j < 2; ++j) {
            zf2[j][nf] = *(const f16x8*)(zr + j * 32 + g * 8);        // z2
            zfh[j][nf] = *(const f16x8*)(zr + 64 + j * 32 + g * 8);   // zh
        }
    }

    int rbase[2], rx[2];
    #pragma unroll
    for (int mf = 0; mf < 2; ++mf) {
        int r = wm * 32 + mf * 16 + c15;
        rbase[mf] = r * 256;
        rx[mf] = (r & 15) << 4;
    }

    auto stage = [&](int ch, int buf) {
        char* dst = smem + buf * 32768;
        const char* src = (const char*)Ee + (size_t)ch * 32768;
        #pragma unroll
        for (int t = 0; t < 4; ++t) {
            int p = t * 8192 + tid * 16;
            int r = p >> 8, b = p & 255;
            gll16(src + r * 256 + (b ^ ((r & 15) << 4)), dst + p);
        }
    };

    float bv[4];
    int   bi[4];
    #pragma unroll
    for (int nf = 0; nf < 4; ++nf) { bv[nf] = 3.402823466e38f; bi[nf] = 0; }

    const f32x4 zz4 = {0.f, 0.f, 0.f, 0.f};
    static const int koffs[6] = {0, 64, 128, 192, 0, 64};

    stage(0, 0);
    __syncthreads();

    for (int ch = 0; ch < 32; ++ch) {
        const int buf = ch & 1;
        f32x4 sqv[2];
        #pragma unroll
        for (int mf = 0; mf < 2; ++mf)
            sqv[mf] = *(const f32x4*)(sqr + ch * 128 + wm * 32 + mf * 16 + g * 4);

        if (ch < 31) stage(ch + 1, buf ^ 1);

        const char* base = smem + buf * 32768;
        f32x4 accL[2][4], accH[2][4];
        #pragma unroll
        for (int j = 0; j < 6; ++j) {
            const int kraw = koffs[j] + g16;
            f16x8 af[2];
            #pragma unroll
            for (int mf = 0; mf < 2; ++mf)
                af[mf] = *(const f16x8*)(base + rbase[mf] + (kraw ^ rx[mf]));
            #pragma unroll
            for (int mf = 0; mf < 2; ++mf) {
                #pragma unroll
                for (int nf = 0; nf < 4; ++nf) {
                    if (j == 0)
                        accL[mf][nf] = __builtin_amdgcn_mfma_f32_16x16x32_f16(
                            af[mf], zf2[0][nf], zz4, 0, 0, 0);
                    else if (j == 1)
                        accL[mf][nf] = __builtin_amdgcn_mfma_f32_16x16x32_f16(
                            af[mf], zf2[1][nf], accL[mf][nf], 0, 0, 0);
                    else if (j < 4)
                        accL[mf][nf] = __builtin_amdgcn_mfma_f32_16x16x32_f16(
                            af[mf], zfh[j - 2][nf], accL[mf][nf], 0, 0, 0);
                    else if (j == 4)
                        accH[mf][nf] = __builtin_amdgcn_mfma_f32_16x16x32_f16(
                            af[mf], zfh[0][nf], zz4, 0, 0, 0);
                    else
                        accH[mf][nf] = __builtin_amdgcn_mfma_f32_16x16x32_f16(
                            af[mf], zfh[1][nf], accH[mf][nf], 0, 0, 0);
                }
            }
        }

        #pragma unroll
        for (int nf = 0; nf < 4; ++nf) {
            #pragma unroll
            for (int mf = 0; mf < 2; ++mf) {
                f32x4 v = sqv[mf] - accH[mf][nf] * 2.0f
                                  - accL[mf][nf] * 0.001953125f;
                #pragma unroll
                for (int r2 = 0; r2 < 4; ++r2) {
                    if (v[r2] < bv[nf]) {
                        bv[nf] = v[r2];
                        bi[nf] = ch * 128 + wm * 32 + mf * 16 + g * 4 + r2;
                    }
                }
            }
        }
        __syncthreads();
    }

    // ---- final reduction: argmin + ||z||^2 + loss partial ----
    float* redv = (float*)(smem + 65536);          // [4][128]
    int*   redi = (int*)(smem + 65536 + 2048);     // [4][128]
    float* zsqa = (float*)(smem + 65536 + 4096);   // [128]

    #pragma unroll
    for (int nf = 0; nf < 4; ++nf) {
        float v_ = bv[nf]; int i_ = bi[nf];
        #pragma unroll
        for (int m = 16; m <= 32; m <<= 1) {
            float ov = __shfl_xor(v_, m);
            int oi = __shfl_xor(i_, m);
            if (ov < v_ || (ov == v_ && oi < i_)) { v_ = ov; i_ = oi; }
        }
        if (g == 0) {
            int rl = wn * 64 + nf * 16 + c15;
            redv[wm * 128 + rl] = v_;
            redi[wm * 128 + rl] = i_;
        }
    }
    // ||z||^2 per row: identical regs across wm-waves; use wm==0 only
    if (wm == 0) {
        #pragma unroll
        for (int nf = 0; nf < 4; ++nf) {
            float s = 0.f;
            #pragma unroll
            for (int j = 0; j < 2; ++j)
                #pragma unroll
                for (int e = 0; e < 8; ++e) {
                    float zv = (float)zfh[j][nf][e]
                             + (float)zf2[j][nf][e] * 0.0009765625f;
                    s += zv * zv;
                }
            s += __shfl_xor(s, 16);
            s += __shfl_xor(s, 32);
            if (g == 0) zsqa[wn * 64 + nf * 16 + c15] = s;
        }
    }
    __syncthreads();
    float lossv = 0.f;
    if (tid < 128) {
        float v0 = redv[tid]; int i0 = redi[tid];
        #pragma unroll
        for (int w = 1; w < 4; ++w) {
            float v1 = redv[w * 128 + tid]; int i1 = redi[w * 128 + tid];
            if (v1 < v0 || (v1 == v0 && i1 < i0)) { v0 = v1; i0 = i1; }
        }
        int grow = row0 + tid;
        idx[grow] = i0;
        out_idx[grow] = (float)i0;
        atomicAdd(&counts[i0], 1);
        lossv = v0 + zsqa[tid];
    }
    __syncthreads();
    // block-sum the 128 loss values (tid<128 = waves 0,1)
    #pragma unroll
    for (int m = 1; m < 64; m <<= 1) lossv += __shfl_xor(lossv, m);
    if (tid == 0)  redv[0] = lossv;
    if (tid == 64) redv[1] = lossv;
    __syncthreads();
    if (tid == 0) lpart[blockIdx.x] = redv[0] + redv[1];
}

// ---------------------------------------------------------------------------
// D = emb @ W_recv + b_recv   [4096,64]x[64,1024]
__global__ __launch_bounds__(256) void k_dec(const float* __restrict__ emb,
                                             const float* __restrict__ Wr,
                                             const float* __restrict__ br,
                                             float* __restrict__ D) {
    __shared__ float Ek[64][68];    // [dim][code]
    __shared__ float Wt[64][132];   // [dim][col]
    int cb0  = (blockIdx.x & 63) * 64;
    int col0 = (blockIdx.x >> 6) * 128;
    int tid = threadIdx.x;
    int tx = tid & 15;
    int ty = tid >> 4;

    for (int q = tid; q < 1024; q += 256) {
        int r = q >> 4, c4 = q & 15;
        float4 v = *(const float4*)&emb[(size_t)(cb0 + r) * DC + c4*4];
        Ek[c4*4+0][r] = v.x; Ek[c4*4+1][r] = v.y;
        Ek[c4*4+2][r] = v.z; Ek[c4*4+3][r] = v.w;
    }
    for (int q = tid; q < 2048; q += 256) {
        int c = q >> 5, k4 = q & 31;
        *(float4*)&Wt[c][k4*4] = *(const float4*)&Wr[(size_t)c * DIN + col0 + k4*4];
    }
    __syncthreads();

    float acc[4][8] = {};
    #pragma unroll 8
    for (int c = 0; c < 64; ++c) {
        float4 av = *(const float4*)&Ek[c][tx*4];
        float4 w0 = *(const float4*)&Wt[c][ty*8];
        float4 w1 = *(const float4*)&Wt[c][ty*8 + 4];
        float a[4] = {av.x, av.y, av.z, av.w};
        float w[8] = {w0.x, w0.y, w0.z, w0.w, w1.x, w1.y, w1.z, w1.w};
        #pragma unroll
        for (int i = 0; i < 4; ++i)
            #pragma unroll
            for (int j = 0; j < 8; ++j)
                acc[i][j] += a[i] * w[j];
    }

    #pragma unroll
    for (int i = 0; i < 4; ++i) {
        int code = cb0 + tx*4 + i;
        float4 o0, o1;
        o0.x = acc[i][0] + br[col0 + ty*8 + 0];
        o0.y = acc[i][1] + br[col0 + ty*8 + 1];
        o0.z = acc[i][2] + br[col0 + ty*8 + 2];
        o0.w = acc[i][3] + br[col0 + ty*8 + 3];
        o1.x = acc[i][4] + br[col0 + ty*8 + 4];
        o1.y = acc[i][5] + br[col0 + ty*8 + 5];
        o1.z = acc[i][6] + br[col0 + ty*8 + 6];
        o1.w = acc[i][7] + br[col0 + ty*8 + 7];
        *(float4*)&D[(size_t)code * DIN + col0 + ty*8]     = o0;
        *(float4*)&D[(size_t)code * DIN + col0 + ty*8 + 4] = o1;
    }
}

// ---------------------------------------------------------------------------
__global__ __launch_bounds__(256) void k_gather(const float* __restrict__ D,
                                                const int* __restrict__ idx,
                                                float* __restrict__ x) {
    int gidx = blockIdx.x * 256 + threadIdx.x;
    #pragma unroll
    for (int it = 0; it < 4; ++it) {
        int f = gidx + it * 524288;
        int row = f >> 6, c = f & 63;
        int code = idx[row];
        *(float4*)&x[(size_t)row * DIN + c*4] =
            *(const float4*)&D[(size_t)code * DIN + c*4];
    }
}

// ---------------------------------------------------------------------------
__global__ __launch_bounds__(256) void k_final(const int* __restrict__ counts,
                                               const float* __restrict__ partials,
                                               float* __restrict__ out_sc) {
    __shared__ float red[256];
    int tid = threadIdx.x;

    red[tid] = partials[tid];
    __syncthreads();
    for (int s = 128; s > 0; s >>= 1) {
        if (tid < s) red[tid] += red[tid + s];
        __syncthreads();
    }
    float loss = red[0];
    __syncthreads();

    float ep = 0.f;
    for (int k = tid; k < KC; k += 256) {
        int c = counts[k];
        if (c > 0) {
            float p = (float)c / 32768.0f;
            ep += p * logf(p);
        }
    }
    red[tid] = ep; __syncthreads();
    for (int s = 128; s > 0; s >>= 1) {
        if (tid < s) red[tid] += red[tid + s];
        __syncthreads();
    }
    if (tid == 0) {
        out_sc[0] = loss;
        out_sc[1] = loss;
        out_sc[2] = -red[0] * 1.4426950408889634f;
    }
}

// ---------------------------------------------------------------------------
extern "C" void kernel_launch(void* const* d_in, const int* in_sizes, int n_in,
                              void* d_out, int out_size, void* d_ws, size_t ws_size,
                              hipStream_t stream) {
    (void)in_sizes; (void)n_in; (void)out_size; (void)ws_size;
    const float* input  = (const float*)d_in[0];
    const float* W_send = (const float*)d_in[1];
    const float* b_send = (const float*)d_in[2];
    const float* emb    = (const float*)d_in[3];
    const float* W_recv = (const float*)d_in[4];
    const float* b_recv = (const float*)d_in[5];
    float* out = (float*)d_out;

    char* ws = (char*)d_ws;
    _Float16* Ze  = (_Float16*)(ws);                  //  8 MB  [32768][128]
    float*    D   = (float*)(ws + 8388608);           // 16 MB  (no alias now)
    _Float16* Ee  = (_Float16*)(ws + 25165824);       //  1 MB  [4096][128]
    float*    sqr = (float*)(ws + 26214400);          // 16 KB
    int*      idx = (int*)  (ws + 26230784);          // 128 KB
    int*   counts = (int*)  (ws + 26361856);          // 16 KB
    float* lpart  = (float*)(ws + 26378240);          //  1 KB (256 floats)
    _Float16* Wh  = (_Float16*)(ws + 26379264);       // 128 KB [64][1024]
    _Float16* Wl  = (_Float16*)(ws + 26510336);       // 128 KB [64][1024]

    float* out_x   = out;                    // 33554432
    float* out_idx = out + 33554432;         // 32768
    float* out_sc  = out + 33587200;         // 3

    k_prep<<<1040, 256, 0, stream>>>(emb, W_send, Ee, sqr, Wh, Wl, counts);
    k_send<<<512, 256, 0, stream>>>(input, Wh, Wl, b_send, Ze);
    k_dec<<<512, 256, 0, stream>>>(emb, W_recv, b_recv, D);
    k_score<<<256, 512, 0, stream>>>(Ee, Ze, sqr, idx, out_idx, counts, lpart);
    k_gather<<<2048, 256, 0, stream>>>(D, idx, out_x);
    k_final<<<1, 256, 0, stream>>>(counts, lpart, out_sc);
}